// Round 5
// baseline (246.185 us; speedup 1.0000x reference)
//
#include <hip/hip_runtime.h>
#include <hip/hip_bf16.h>
#include <math.h>

#define IN_CH 128

typedef __attribute__((ext_vector_type(8))) short bf16x8;
typedef __attribute__((ext_vector_type(4))) float f32x4;

__device__ __forceinline__ ushort f2b(float f) {
    union { float f; uint u; } c; c.f = f;
    uint u = c.u + 0x7fff + ((c.u >> 16) & 1);   // RNE
    return (ushort)(u >> 16);
}
__device__ __forceinline__ float b2f(uint hi16) {
    union { uint u; float f; } c; c.u = hi16 << 16;
    return c.f;
}

// ---------------- fused prep: x->bf16, zero deg, 4 weight transposes ----------------
__global__ __launch_bounds__(256) void prep(const float* __restrict__ x,
                                            ushort* __restrict__ xb, int n8,
                                            int* __restrict__ degI, int nz,
                                            const float* __restrict__ Wl1,
                                            const float* __restrict__ Wr1,
                                            const float* __restrict__ Wl2,
                                            const float* __restrict__ Wr2,
                                            ushort* __restrict__ WlT1,
                                            ushort* __restrict__ WrT1,
                                            ushort* __restrict__ WlT2,
                                            ushort* __restrict__ WrT2) {
    int i = blockIdx.x * 256 + threadIdx.x;
    if (i < nz) degI[i] = 0;
    if (i < n8) {
        float4 a = ((const float4*)x)[2 * i];
        float4 b = ((const float4*)x)[2 * i + 1];
        union { ushort u[8]; uint4 v; } p;
        p.u[0] = f2b(a.x); p.u[1] = f2b(a.y); p.u[2] = f2b(a.z); p.u[3] = f2b(a.w);
        p.u[4] = f2b(b.x); p.u[5] = f2b(b.y); p.u[6] = f2b(b.z); p.u[7] = f2b(b.w);
        ((uint4*)xb)[i] = p.v;
    } else {
        int w = i - n8;
        if (w < 2 * 16384 + 2 * 8192) {
            const float* W; ushort* Wt; int N, r;
            if (w < 16384)      { W = Wl1; Wt = WlT1; N = 128; r = w; }
            else if (w < 32768) { W = Wr1; Wt = WrT1; N = 128; r = w - 16384; }
            else if (w < 40960) { W = Wl2; Wt = WlT2; N = 64;  r = w - 32768; }
            else                { W = Wr2; Wt = WrT2; N = 64;  r = w - 40960; }
            int n = r / 128, k = r % 128;
            Wt[n * 128 + k] = f2b(W[(size_t)k * N + n]);
        }
    }
}

// ---------------- degree histogram + per-edge rank ----------------
__global__ __launch_bounds__(256) void deg_hist(const int* __restrict__ dst,
                                                int* __restrict__ deg,
                                                int* __restrict__ rank, int nE) {
    int i = blockIdx.x * 256 + threadIdx.x;
    if (i < nE) rank[i] = atomicAdd(&deg[dst[i]], 1);
}

// ---------------- scan k1: each block (256 thr) reduces 1024 elems -> bsum[blk] ----------------
__global__ __launch_bounds__(256) void scan_k1(const int* __restrict__ deg,
                                               int* __restrict__ bsum, int n) {
    int base = blockIdx.x * 1024 + threadIdx.x * 4;
    int s = 0;
    #pragma unroll
    for (int k = 0; k < 4; ++k) { int idx = base + k; if (idx < n) s += deg[idx]; }
    #pragma unroll
    for (int off = 1; off < 64; off <<= 1) s += __shfl_xor(s, off);
    __shared__ int ws[4];
    int lane = threadIdx.x & 63, wid = threadIdx.x >> 6;
    if (lane == 0) ws[wid] = s;
    __syncthreads();
    if (threadIdx.x == 0) bsum[blockIdx.x] = ws[0] + ws[1] + ws[2] + ws[3];
}

// ---------------- scan k3: block offset from bsum (inline reduce), rescan 1024 elems ----------------
__global__ __launch_bounds__(256) void scan_k3(const int* __restrict__ deg,
                                               const int* __restrict__ bsum,
                                               int* __restrict__ row_ptr, int n, int nE) {
    __shared__ int s_off;
    if (threadIdx.x < 64) {
        int v = (threadIdx.x < blockIdx.x) ? bsum[threadIdx.x] : 0;  // gridDim <= 64
        #pragma unroll
        for (int off = 32; off >= 1; off >>= 1) v += __shfl_xor(v, off);
        if (threadIdx.x == 0) s_off = v;
    }
    if (blockIdx.x == 0 && threadIdx.x == 0) row_ptr[n] = nE;
    __syncthreads();

    int base = blockIdx.x * 1024 + threadIdx.x * 4;
    int v[4];
    int tsum = 0;
    #pragma unroll
    for (int k = 0; k < 4; ++k) {
        int idx = base + k;
        v[k] = (idx < n) ? deg[idx] : 0;
        tsum += v[k];
    }
    int lane = threadIdx.x & 63, wid = threadIdx.x >> 6;
    int incl = tsum;
    #pragma unroll
    for (int off = 1; off < 64; off <<= 1) {
        int t = __shfl_up(incl, off);
        if (lane >= off) incl += t;
    }
    __shared__ int ws[4];
    if (lane == 63) ws[wid] = incl;
    __syncthreads();
    int woff = 0;
    #pragma unroll
    for (int w = 0; w < 4; ++w) woff += (w < wid) ? ws[w] : 0;
    int off = s_off + woff + (incl - tsum);
    #pragma unroll
    for (int k = 0; k < 4; ++k) {
        int idx = base + k;
        if (idx < n) row_ptr[idx] = off;
        off += v[k];
    }
}

// ---------------- scatter edges into CSR (no atomics; rank precomputed) ----------------
__global__ __launch_bounds__(256) void scatter_edges(const int* __restrict__ src,
                                                     const int* __restrict__ dst,
                                                     const int* __restrict__ row_ptr,
                                                     const int* __restrict__ rank,
                                                     int* __restrict__ ssrc, int nE) {
    int i = blockIdx.x * 256 + threadIdx.x;
    if (i < nE) {
        int d = dst[i];
        ssrc[row_ptr[d] + rank[i]] = src[i];
    }
}

// ---------------- fully fused SAGE layer: agg (in-register) + dual MFMA GEMM ----------------
// feat: [nN][128] bf16 — both gather source and self features.
// Lane (g=lane>>4, r=lane&15) aggregates channels {c*32+g*8 .. +7} (c=0..3) of node
// m0+wave*16+r directly into the MFMA A-fragment layout. Per wave-iteration: 4 vmem
// instrs fetch 16 edge-rows (16 x 64B segments per instr). Degree divergence handled
// by predication (no wasted traffic). Then dual 16x16x32 MFMA:
//   out = act(agg@Wl + bias + self@Wr), optional fused log_softmax (N==64).
template <int NT, bool RELU, bool OUTBF, bool LOGSM>
__global__ __launch_bounds__(256) void sage_fused(const ushort* __restrict__ feat,
                                                  const int* __restrict__ row_ptr,
                                                  const int* __restrict__ ssrc,
                                                  const ushort* __restrict__ WlT,
                                                  const ushort* __restrict__ WrT,
                                                  const float* __restrict__ bias,
                                                  void* __restrict__ outp, int nRows) {
    const int lane = threadIdx.x & 63;
    const int wave = threadIdx.x >> 6;
    const int m0 = blockIdx.x * 64 + wave * 16;
    const int r = lane & 15, g = lane >> 4;
    const int row = m0 + r;
    const bool valid = row < nRows;
    const int rowc = valid ? row : nRows - 1;

    // ---- aggregation phase ----
    int beg = 0, deg = 0;
    if (valid) { beg = row_ptr[row]; deg = row_ptr[row + 1] - beg; }
    int dm = deg;
    #pragma unroll
    for (int off = 8; off >= 1; off >>= 1) dm = max(dm, __shfl_xor(dm, off));
    // dm = max degree over the 16-node group (deg depends only on r) -> wave-uniform

    float a[4][8];
    #pragma unroll
    for (int c = 0; c < 4; ++c)
        #pragma unroll
        for (int e = 0; e < 8; ++e) a[c][e] = 0.f;

    const ushort* fg = feat + g * 8;   // lane's channel-column base
    int j = 0;
    for (; j + 2 <= dm; j += 2) {
        bool a0 = j < deg, a1 = (j + 1) < deg;
        int s0 = 0, s1 = 0;
        if (a0) s0 = ssrc[beg + j];
        if (a1) s1 = ssrc[beg + j + 1];
        bf16x8 v0[4], v1[4];
        if (a0) {
            const ushort* p = fg + (size_t)s0 * IN_CH;
            #pragma unroll
            for (int c = 0; c < 4; ++c) v0[c] = *(const bf16x8*)(p + c * 32);
        }
        if (a1) {
            const ushort* p = fg + (size_t)s1 * IN_CH;
            #pragma unroll
            for (int c = 0; c < 4; ++c) v1[c] = *(const bf16x8*)(p + c * 32);
        }
        if (a0) {
            #pragma unroll
            for (int c = 0; c < 4; ++c)
                #pragma unroll
                for (int e = 0; e < 8; ++e) a[c][e] += b2f((ushort)v0[c][e]);
        }
        if (a1) {
            #pragma unroll
            for (int c = 0; c < 4; ++c)
                #pragma unroll
                for (int e = 0; e < 8; ++e) a[c][e] += b2f((ushort)v1[c][e]);
        }
    }
    if (j < dm) {
        if (j < deg) {
            int s = ssrc[beg + j];
            const ushort* p = fg + (size_t)s * IN_CH;
            #pragma unroll
            for (int c = 0; c < 4; ++c) {
                bf16x8 v = *(const bf16x8*)(p + c * 32);
                #pragma unroll
                for (int e = 0; e < 8; ++e) a[c][e] += b2f((ushort)v[e]);
            }
        }
    }

    // mean + round to bf16 A-fragments
    float inv = 1.0f / fmaxf((float)deg, 1.0f);
    bf16x8 af[4];
    #pragma unroll
    for (int c = 0; c < 4; ++c)
        #pragma unroll
        for (int e = 0; e < 8; ++e) af[c][e] = (short)f2b(a[c][e] * inv);

    // ---- GEMM phase ----
    f32x4 acc[NT];
    #pragma unroll
    for (int i = 0; i < NT; ++i) acc[i] = (f32x4){0.f, 0.f, 0.f, 0.f};

    // aggregated side: A = af, B = WlT
    #pragma unroll
    for (int c = 0; c < 4; ++c) {
        #pragma unroll
        for (int nt = 0; nt < NT; ++nt) {
            bf16x8 bfv = *(const bf16x8*)(WlT + (size_t)(nt * 16 + r) * 128 + c * 32 + g * 8);
            acc[nt] = __builtin_amdgcn_mfma_f32_16x16x32_bf16(af[c], bfv, acc[nt], 0, 0, 0);
        }
    }
    // self side: A = feat[rowc], B = WrT
    const ushort* arow = feat + (size_t)rowc * IN_CH + g * 8;
    #pragma unroll
    for (int c = 0; c < 4; ++c) {
        bf16x8 sf = *(const bf16x8*)(arow + c * 32);
        #pragma unroll
        for (int nt = 0; nt < NT; ++nt) {
            bf16x8 bfv = *(const bf16x8*)(WrT + (size_t)(nt * 16 + r) * 128 + c * 32 + g * 8);
            acc[nt] = __builtin_amdgcn_mfma_f32_16x16x32_bf16(sf, bfv, acc[nt], 0, 0, 0);
        }
    }

    constexpr int N = NT * 16;
    const int rbase = m0 + g * 4;

    float bv[NT];
    #pragma unroll
    for (int nt = 0; nt < NT; ++nt) bv[nt] = bias[nt * 16 + r];

    if (LOGSM) {
        #pragma unroll
        for (int q = 0; q < 4; ++q) {
            float m = -1e30f;
            #pragma unroll
            for (int nt = 0; nt < NT; ++nt) m = fmaxf(m, acc[nt][q] + bv[nt]);
            #pragma unroll
            for (int off = 8; off >= 1; off >>= 1) m = fmaxf(m, __shfl_xor(m, off));
            float s = 0.f;
            #pragma unroll
            for (int nt = 0; nt < NT; ++nt) s += expf(acc[nt][q] + bv[nt] - m);
            #pragma unroll
            for (int off = 8; off >= 1; off >>= 1) s += __shfl_xor(s, off);
            float lse = m + logf(s);
            if (rbase + q < nRows) {
                float* orow = (float*)outp + (size_t)(rbase + q) * N;
                #pragma unroll
                for (int nt = 0; nt < NT; ++nt)
                    orow[nt * 16 + r] = acc[nt][q] + bv[nt] - lse;
            }
        }
    } else {
        #pragma unroll
        for (int nt = 0; nt < NT; ++nt) {
            #pragma unroll
            for (int q = 0; q < 4; ++q) {
                if (rbase + q < nRows) {
                    float v = acc[nt][q] + bv[nt];
                    if (RELU) v = fmaxf(v, 0.f);
                    if (OUTBF)
                        ((ushort*)outp)[(size_t)(rbase + q) * N + nt * 16 + r] = f2b(v);
                    else
                        ((float*)outp)[(size_t)(rbase + q) * N + nt * 16 + r] = v;
                }
            }
        }
    }
}

extern "C" void kernel_launch(void* const* d_in, const int* in_sizes, int n_in,
                              void* d_out, int out_size, void* d_ws, size_t ws_size,
                              hipStream_t stream) {
    const float* x   = (const float*)d_in[0];
    const int* edges = (const int*)d_in[1];
    const float* Wl1 = (const float*)d_in[2];
    const float* bl1 = (const float*)d_in[3];
    const float* Wr1 = (const float*)d_in[4];
    const float* Wl2 = (const float*)d_in[5];
    const float* bl2 = (const float*)d_in[6];
    const float* Wr2 = (const float*)d_in[7];
    float* out = (float*)d_out;

    const int nN = in_sizes[0] / IN_CH;   // 50000
    const int nE = in_sizes[1] / 2;       // 600000

    // workspace carve
    ushort* xb   = (ushort*)d_ws;                 // nN*128 bf16
    ushort* h    = xb + (size_t)nN * IN_CH;       // nN*128 bf16
    ushort* WlT1 = h + (size_t)nN * IN_CH;        // 128*128
    ushort* WrT1 = WlT1 + 128 * 128;              // 128*128
    ushort* WlT2 = WrT1 + 128 * 128;              // 64*128
    ushort* WrT2 = WlT2 + 64 * 128;               // 64*128
    int* degI    = (int*)(WrT2 + 64 * 128);       // nN
    int* row_ptr = degI + nN;                     // nN+1
    int* bsum    = row_ptr + (nN + 1);            // <=64
    int* ssrc    = bsum + 64;                     // nE
    int* rank    = ssrc + nE;                     // nE

    const int* esrc = edges;
    const int* edst = edges + nE;

    const int n8 = nN * IN_CH / 8;                // 800000
    const int nb = (nN + 1023) / 1024;            // 49 (<=64 required)

    prep<<<(n8 + 49152 + 255) / 256, 256, 0, stream>>>(x, xb, n8, degI, nN,
                                                       Wl1, Wr1, Wl2, Wr2,
                                                       WlT1, WrT1, WlT2, WrT2);

    deg_hist<<<(nE + 255) / 256, 256, 0, stream>>>(edst, degI, rank, nE);
    scan_k1<<<nb, 256, 0, stream>>>(degI, bsum, nN);
    scan_k3<<<nb, 256, 0, stream>>>(degI, bsum, row_ptr, nN, nE);
    scatter_edges<<<(nE + 255) / 256, 256, 0, stream>>>(esrc, edst, row_ptr, rank, ssrc, nE);

    // layer 1: h = relu(mean_agg(xb)@Wl1 + bl1 + xb@Wr1), bf16 out
    sage_fused<8, true, true, false><<<(nN + 63) / 64, 256, 0, stream>>>(
        xb, row_ptr, ssrc, WlT1, WrT1, bl1, h, nN);

    // layer 2: out = log_softmax(mean_agg(h)@Wl2 + bl2 + h@Wr2)
    sage_fused<4, false, false, true><<<(nN + 63) / 64, 256, 0, stream>>>(
        h, row_ptr, ssrc, WlT2, WrT2, bl2, out, nN);
}

// Round 6
// 239.458 us; speedup vs baseline: 1.0281x; 1.0281x over previous
//
#include <hip/hip_runtime.h>
#include <hip/hip_bf16.h>
#include <math.h>

#define IN_CH 128

typedef __attribute__((ext_vector_type(8))) short bf16x8;
typedef __attribute__((ext_vector_type(4))) float f32x4;

__device__ __forceinline__ ushort f2b(float f) {
    union { float f; uint u; } c; c.f = f;
    uint u = c.u + 0x7fff + ((c.u >> 16) & 1);   // RNE
    return (ushort)(u >> 16);
}
__device__ __forceinline__ float b2f(uint hi16) {
    union { uint u; float f; } c; c.u = hi16 << 16;
    return c.f;
}

// ---------------- fused prep: x->bf16, zero deg, 4 weight transposes ----------------
__global__ __launch_bounds__(256) void prep(const float* __restrict__ x,
                                            ushort* __restrict__ xb, int n8,
                                            int* __restrict__ degI, int nz,
                                            const float* __restrict__ Wl1,
                                            const float* __restrict__ Wr1,
                                            const float* __restrict__ Wl2,
                                            const float* __restrict__ Wr2,
                                            ushort* __restrict__ WlT1,
                                            ushort* __restrict__ WrT1,
                                            ushort* __restrict__ WlT2,
                                            ushort* __restrict__ WrT2) {
    int i = blockIdx.x * 256 + threadIdx.x;
    if (i < nz) degI[i] = 0;
    if (i < n8) {
        float4 a = ((const float4*)x)[2 * i];
        float4 b = ((const float4*)x)[2 * i + 1];
        union { ushort u[8]; uint4 v; } p;
        p.u[0] = f2b(a.x); p.u[1] = f2b(a.y); p.u[2] = f2b(a.z); p.u[3] = f2b(a.w);
        p.u[4] = f2b(b.x); p.u[5] = f2b(b.y); p.u[6] = f2b(b.z); p.u[7] = f2b(b.w);
        ((uint4*)xb)[i] = p.v;
    } else {
        int w = i - n8;
        if (w < 2 * 16384 + 2 * 8192) {
            const float* W; ushort* Wt; int N, r;
            if (w < 16384)      { W = Wl1; Wt = WlT1; N = 128; r = w; }
            else if (w < 32768) { W = Wr1; Wt = WrT1; N = 128; r = w - 16384; }
            else if (w < 40960) { W = Wl2; Wt = WlT2; N = 64;  r = w - 32768; }
            else                { W = Wr2; Wt = WrT2; N = 64;  r = w - 40960; }
            int n = r / 128, k = r % 128;
            Wt[n * 128 + k] = f2b(W[(size_t)k * N + n]);
        }
    }
}

// ---------------- degree histogram + per-edge rank ----------------
__global__ __launch_bounds__(256) void deg_hist(const int* __restrict__ dst,
                                                int* __restrict__ deg,
                                                int* __restrict__ rank, int nE) {
    int i = blockIdx.x * 256 + threadIdx.x;
    if (i < nE) rank[i] = atomicAdd(&deg[dst[i]], 1);
}

// ---------------- scan k1: each block (256 thr) reduces 1024 elems -> bsum[blk] ----------------
__global__ __launch_bounds__(256) void scan_k1(const int* __restrict__ deg,
                                               int* __restrict__ bsum, int n) {
    int base = blockIdx.x * 1024 + threadIdx.x * 4;
    int s = 0;
    #pragma unroll
    for (int k = 0; k < 4; ++k) { int idx = base + k; if (idx < n) s += deg[idx]; }
    #pragma unroll
    for (int off = 1; off < 64; off <<= 1) s += __shfl_xor(s, off);
    __shared__ int ws[4];
    int lane = threadIdx.x & 63, wid = threadIdx.x >> 6;
    if (lane == 0) ws[wid] = s;
    __syncthreads();
    if (threadIdx.x == 0) bsum[blockIdx.x] = ws[0] + ws[1] + ws[2] + ws[3];
}

// ---------------- scan k3: block offset from bsum (inline reduce), rescan 1024 elems ----------------
__global__ __launch_bounds__(256) void scan_k3(const int* __restrict__ deg,
                                               const int* __restrict__ bsum,
                                               int* __restrict__ row_ptr, int n, int nE) {
    __shared__ int s_off;
    if (threadIdx.x < 64) {
        int v = (threadIdx.x < blockIdx.x) ? bsum[threadIdx.x] : 0;  // gridDim <= 64
        #pragma unroll
        for (int off = 32; off >= 1; off >>= 1) v += __shfl_xor(v, off);
        if (threadIdx.x == 0) s_off = v;
    }
    if (blockIdx.x == 0 && threadIdx.x == 0) row_ptr[n] = nE;
    __syncthreads();

    int base = blockIdx.x * 1024 + threadIdx.x * 4;
    int v[4];
    int tsum = 0;
    #pragma unroll
    for (int k = 0; k < 4; ++k) {
        int idx = base + k;
        v[k] = (idx < n) ? deg[idx] : 0;
        tsum += v[k];
    }
    int lane = threadIdx.x & 63, wid = threadIdx.x >> 6;
    int incl = tsum;
    #pragma unroll
    for (int off = 1; off < 64; off <<= 1) {
        int t = __shfl_up(incl, off);
        if (lane >= off) incl += t;
    }
    __shared__ int ws[4];
    if (lane == 63) ws[wid] = incl;
    __syncthreads();
    int woff = 0;
    #pragma unroll
    for (int w = 0; w < 4; ++w) woff += (w < wid) ? ws[w] : 0;
    int off = s_off + woff + (incl - tsum);
    #pragma unroll
    for (int k = 0; k < 4; ++k) {
        int idx = base + k;
        if (idx < n) row_ptr[idx] = off;
        off += v[k];
    }
}

// ---------------- scatter edges into CSR (no atomics; rank precomputed) ----------------
__global__ __launch_bounds__(256) void scatter_edges(const int* __restrict__ src,
                                                     const int* __restrict__ dst,
                                                     const int* __restrict__ row_ptr,
                                                     const int* __restrict__ rank,
                                                     int* __restrict__ ssrc, int nE) {
    int i = blockIdx.x * 256 + threadIdx.x;
    if (i < nE) {
        int d = dst[i];
        ssrc[row_ptr[d] + rank[i]] = src[i];
    }
}

// ---------------- fused SAGE layer, K-split gather over 4 waves ----------------
// Block = 16 output rows, 4 waves. Wave w aggregates edges j === w (mod 4) of the
// 16 rows into f32 partials (MFMA A-fragment layout: lane (g,r) holds channels
// c*32+g*8..+7 of row m0+r). Partials combined via LDS [4][32][64] (bank = lane%32,
// only free 2-way lane/lane+32 aliasing). Then dual 16x16x32 MFMA:
//   out = act(mean_agg@Wl + bias + self@Wr)
// COLSPLIT: waves compute disjoint nt quarters (layer 1). LOGSM: wave 0 computes
// the full N=64 + intra-wave log_softmax; waves 1-3 exit after partial deposit.
template <int NT, bool RELU, bool OUTBF, bool LOGSM, bool COLSPLIT>
__global__ __launch_bounds__(256) void sage_fused(const ushort* __restrict__ feat,
                                                  const int* __restrict__ row_ptr,
                                                  const int* __restrict__ ssrc,
                                                  const ushort* __restrict__ WlT,
                                                  const ushort* __restrict__ WrT,
                                                  const float* __restrict__ bias,
                                                  void* __restrict__ outp, int nRows) {
    constexpr int NTW = COLSPLIT ? NT / 4 : NT;
    __shared__ float part[4][32][64];                // 32 KiB

    const int lane = threadIdx.x & 63;
    const int w = threadIdx.x >> 6;
    const int m0 = blockIdx.x * 16;
    const int r = lane & 15, g = lane >> 4;
    const int row = m0 + r;
    const bool valid = row < nRows;
    const int rowc = valid ? row : nRows - 1;

    int beg = 0, deg = 0;
    if (valid) { beg = row_ptr[row]; deg = row_ptr[row + 1] - beg; }
    int dm = deg;
    #pragma unroll
    for (int off = 8; off >= 1; off >>= 1) dm = max(dm, __shfl_xor(dm, off));
    // dm: max degree over the 16-row group (wave-uniform)

    float a[4][8];
    #pragma unroll
    for (int c = 0; c < 4; ++c)
        #pragma unroll
        for (int e = 0; e < 8; ++e) a[c][e] = 0.f;

    const ushort* fg = feat + g * 8;
    int j = w;
    for (; j + 4 < dm; j += 8) {                     // edges j, j+4 (stride-4 slice)
        bool p0 = j < deg, p1 = (j + 4) < deg;
        int s0 = 0, s1 = 0;
        if (p0) s0 = ssrc[beg + j];
        if (p1) s1 = ssrc[beg + j + 4];
        bf16x8 v0[4], v1[4];
        if (p0) {
            const ushort* p = fg + (size_t)s0 * IN_CH;
            #pragma unroll
            for (int c = 0; c < 4; ++c) v0[c] = *(const bf16x8*)(p + c * 32);
        }
        if (p1) {
            const ushort* p = fg + (size_t)s1 * IN_CH;
            #pragma unroll
            for (int c = 0; c < 4; ++c) v1[c] = *(const bf16x8*)(p + c * 32);
        }
        if (p0) {
            #pragma unroll
            for (int c = 0; c < 4; ++c)
                #pragma unroll
                for (int e = 0; e < 8; ++e) a[c][e] += b2f((ushort)v0[c][e]);
        }
        if (p1) {
            #pragma unroll
            for (int c = 0; c < 4; ++c)
                #pragma unroll
                for (int e = 0; e < 8; ++e) a[c][e] += b2f((ushort)v1[c][e]);
        }
    }
    if (j < dm && j < deg) {
        int s = ssrc[beg + j];
        const ushort* p = fg + (size_t)s * IN_CH;
        #pragma unroll
        for (int c = 0; c < 4; ++c) {
            bf16x8 v = *(const bf16x8*)(p + c * 32);
            #pragma unroll
            for (int e = 0; e < 8; ++e) a[c][e] += b2f((ushort)v[e]);
        }
    }

    // deposit partials, combine across waves
    #pragma unroll
    for (int i = 0; i < 32; ++i) part[w][i][lane] = a[i >> 3][i & 7];
    __syncthreads();
    if (LOGSM && w != 0) return;                     // wave 0 finishes layer 2

    float inv = 1.0f / fmaxf((float)deg, 1.0f);
    bf16x8 af[4];
    #pragma unroll
    for (int c = 0; c < 4; ++c)
        #pragma unroll
        for (int e = 0; e < 8; ++e) {
            float s = part[0][c * 8 + e][lane] + part[1][c * 8 + e][lane]
                    + part[2][c * 8 + e][lane] + part[3][c * 8 + e][lane];
            af[c][e] = (short)f2b(s * inv);
        }

    // ---- GEMM phase ----
    const int ntoff = COLSPLIT ? w * NTW : 0;
    f32x4 acc[NTW];
    #pragma unroll
    for (int i = 0; i < NTW; ++i) acc[i] = (f32x4){0.f, 0.f, 0.f, 0.f};

    #pragma unroll
    for (int c = 0; c < 4; ++c) {
        #pragma unroll
        for (int t = 0; t < NTW; ++t) {
            bf16x8 bfv = *(const bf16x8*)(WlT + (size_t)((ntoff + t) * 16 + r) * 128 + c * 32 + g * 8);
            acc[t] = __builtin_amdgcn_mfma_f32_16x16x32_bf16(af[c], bfv, acc[t], 0, 0, 0);
        }
    }
    const ushort* arow = feat + (size_t)rowc * IN_CH + g * 8;
    #pragma unroll
    for (int c = 0; c < 4; ++c) {
        bf16x8 sf = *(const bf16x8*)(arow + c * 32);
        #pragma unroll
        for (int t = 0; t < NTW; ++t) {
            bf16x8 bfv = *(const bf16x8*)(WrT + (size_t)((ntoff + t) * 16 + r) * 128 + c * 32 + g * 8);
            acc[t] = __builtin_amdgcn_mfma_f32_16x16x32_bf16(sf, bfv, acc[t], 0, 0, 0);
        }
    }

    constexpr int N = NT * 16;
    const int rbase = m0 + g * 4;

    float bv[NTW];
    #pragma unroll
    for (int t = 0; t < NTW; ++t) bv[t] = bias[(ntoff + t) * 16 + r];

    if (LOGSM) {
        #pragma unroll
        for (int q = 0; q < 4; ++q) {
            float m = -1e30f;
            #pragma unroll
            for (int t = 0; t < NTW; ++t) m = fmaxf(m, acc[t][q] + bv[t]);
            #pragma unroll
            for (int off = 8; off >= 1; off >>= 1) m = fmaxf(m, __shfl_xor(m, off));
            float s = 0.f;
            #pragma unroll
            for (int t = 0; t < NTW; ++t) s += expf(acc[t][q] + bv[t] - m);
            #pragma unroll
            for (int off = 8; off >= 1; off >>= 1) s += __shfl_xor(s, off);
            float lse = m + logf(s);
            if (rbase + q < nRows) {
                float* orow = (float*)outp + (size_t)(rbase + q) * N;
                #pragma unroll
                for (int t = 0; t < NTW; ++t)
                    orow[t * 16 + r] = acc[t][q] + bv[t] - lse;
            }
        }
    } else {
        #pragma unroll
        for (int t = 0; t < NTW; ++t) {
            #pragma unroll
            for (int q = 0; q < 4; ++q) {
                if (rbase + q < nRows) {
                    float v = acc[t][q] + bv[t];
                    if (RELU) v = fmaxf(v, 0.f);
                    if (OUTBF)
                        ((ushort*)outp)[(size_t)(rbase + q) * N + (ntoff + t) * 16 + r] = f2b(v);
                    else
                        ((float*)outp)[(size_t)(rbase + q) * N + (ntoff + t) * 16 + r] = v;
                }
            }
        }
    }
}

extern "C" void kernel_launch(void* const* d_in, const int* in_sizes, int n_in,
                              void* d_out, int out_size, void* d_ws, size_t ws_size,
                              hipStream_t stream) {
    const float* x   = (const float*)d_in[0];
    const int* edges = (const int*)d_in[1];
    const float* Wl1 = (const float*)d_in[2];
    const float* bl1 = (const float*)d_in[3];
    const float* Wr1 = (const float*)d_in[4];
    const float* Wl2 = (const float*)d_in[5];
    const float* bl2 = (const float*)d_in[6];
    const float* Wr2 = (const float*)d_in[7];
    float* out = (float*)d_out;

    const int nN = in_sizes[0] / IN_CH;   // 50000
    const int nE = in_sizes[1] / 2;       // 600000

    // workspace carve
    ushort* xb   = (ushort*)d_ws;                 // nN*128 bf16
    ushort* h    = xb + (size_t)nN * IN_CH;       // nN*128 bf16
    ushort* WlT1 = h + (size_t)nN * IN_CH;        // 128*128
    ushort* WrT1 = WlT1 + 128 * 128;              // 128*128
    ushort* WlT2 = WrT1 + 128 * 128;              // 64*128
    ushort* WrT2 = WlT2 + 64 * 128;               // 64*128
    int* degI    = (int*)(WrT2 + 64 * 128);       // nN
    int* row_ptr = degI + nN;                     // nN+1
    int* bsum    = row_ptr + (nN + 1);            // <=64
    int* ssrc    = bsum + 64;                     // nE
    int* rank    = ssrc + nE;                     // nE

    const int* esrc = edges;
    const int* edst = edges + nE;

    const int n8 = nN * IN_CH / 8;                // 800000
    const int nb = (nN + 1023) / 1024;            // 49 (<=64 required)

    prep<<<(n8 + 49152 + 255) / 256, 256, 0, stream>>>(x, xb, n8, degI, nN,
                                                       Wl1, Wr1, Wl2, Wr2,
                                                       WlT1, WrT1, WlT2, WrT2);

    deg_hist<<<(nE + 255) / 256, 256, 0, stream>>>(edst, degI, rank, nE);
    scan_k1<<<nb, 256, 0, stream>>>(degI, bsum, nN);
    scan_k3<<<nb, 256, 0, stream>>>(degI, bsum, row_ptr, nN, nE);
    scatter_edges<<<(nE + 255) / 256, 256, 0, stream>>>(esrc, edst, row_ptr, rank, ssrc, nE);

    // layer 1: h = relu(mean_agg(xb)@Wl1 + bl1 + xb@Wr1), bf16 out, column-split waves
    sage_fused<8, true, true, false, true><<<(nN + 15) / 16, 256, 0, stream>>>(
        xb, row_ptr, ssrc, WlT1, WrT1, bl1, h, nN);

    // layer 2: out = log_softmax(mean_agg(h)@Wl2 + bl2 + h@Wr2), wave-0 epilogue
    sage_fused<4, false, false, true, false><<<(nN + 15) / 16, 256, 0, stream>>>(
        h, row_ptr, ssrc, WlT2, WrT2, bl2, out, nN);
}

// Round 7
// 238.147 us; speedup vs baseline: 1.0338x; 1.0055x over previous
//
#include <hip/hip_runtime.h>
#include <hip/hip_bf16.h>
#include <math.h>

#define IN_CH 128

typedef __attribute__((ext_vector_type(8))) short bf16x8;
typedef __attribute__((ext_vector_type(4))) float f32x4;

__device__ __forceinline__ ushort f2b(float f) {
    union { float f; uint u; } c; c.f = f;
    uint u = c.u + 0x7fff + ((c.u >> 16) & 1);   // RNE
    return (ushort)(u >> 16);
}
__device__ __forceinline__ float b2f(uint hi16) {
    union { uint u; float f; } c; c.u = hi16 << 16;
    return c.f;
}

// ---------------- fused prep: x->bf16, zero deg+flags, 4 weight transposes ----------------
__global__ __launch_bounds__(256) void prep(const float* __restrict__ x,
                                            ushort* __restrict__ xb, int n8,
                                            int* __restrict__ zbuf, int nz,
                                            const float* __restrict__ Wl1,
                                            const float* __restrict__ Wr1,
                                            const float* __restrict__ Wl2,
                                            const float* __restrict__ Wr2,
                                            ushort* __restrict__ WlT1,
                                            ushort* __restrict__ WrT1,
                                            ushort* __restrict__ WlT2,
                                            ushort* __restrict__ WrT2) {
    int i = blockIdx.x * 256 + threadIdx.x;
    if (i < nz) zbuf[i] = 0;
    if (i < n8) {
        float4 a = ((const float4*)x)[2 * i];
        float4 b = ((const float4*)x)[2 * i + 1];
        union { ushort u[8]; uint4 v; } p;
        p.u[0] = f2b(a.x); p.u[1] = f2b(a.y); p.u[2] = f2b(a.z); p.u[3] = f2b(a.w);
        p.u[4] = f2b(b.x); p.u[5] = f2b(b.y); p.u[6] = f2b(b.z); p.u[7] = f2b(b.w);
        ((uint4*)xb)[i] = p.v;
    } else {
        int w = i - n8;
        if (w < 2 * 16384 + 2 * 8192) {
            const float* W; ushort* Wt; int N, r;
            if (w < 16384)      { W = Wl1; Wt = WlT1; N = 128; r = w; }
            else if (w < 32768) { W = Wr1; Wt = WrT1; N = 128; r = w - 16384; }
            else if (w < 40960) { W = Wl2; Wt = WlT2; N = 64;  r = w - 32768; }
            else                { W = Wr2; Wt = WrT2; N = 64;  r = w - 40960; }
            int n = r / 128, k = r % 128;
            Wt[n * 128 + k] = f2b(W[(size_t)k * N + n]);
        }
    }
}

// ---------------- degree histogram + per-edge rank ----------------
__global__ __launch_bounds__(256) void deg_hist(const int* __restrict__ dst,
                                                int* __restrict__ deg,
                                                int* __restrict__ rank, int nE) {
    int i = blockIdx.x * 256 + threadIdx.x;
    if (i < nE) rank[i] = atomicAdd(&deg[dst[i]], 1);
}

// ---------------- single-pass exclusive scan (49 blocks, co-resident publish+spin) ----------------
// Safe: gridDim (<=64) <= CU count -> all blocks resident; every block publishes its
// local sum BEFORE spinning on others -> no circular wait.
__global__ __launch_bounds__(256) void scan_fused(const int* __restrict__ deg,
                                                  int* __restrict__ bsum,
                                                  int* __restrict__ flags,
                                                  int* __restrict__ row_ptr,
                                                  int n, int nE) {
    const int tid = threadIdx.x, lane = tid & 63, wid = tid >> 6;
    const int base = blockIdx.x * 1024 + tid * 4;
    int v[4];
    int tsum = 0;
    #pragma unroll
    for (int k = 0; k < 4; ++k) {
        int idx = base + k;
        v[k] = (idx < n) ? deg[idx] : 0;
        tsum += v[k];
    }
    int incl = tsum;
    #pragma unroll
    for (int off = 1; off < 64; off <<= 1) {
        int t = __shfl_up(incl, off);
        if (lane >= off) incl += t;
    }
    __shared__ int ws[4];
    if (lane == 63) ws[wid] = incl;
    __syncthreads();
    if (tid == 0) {
        int btot = ws[0] + ws[1] + ws[2] + ws[3];
        __hip_atomic_store(&bsum[blockIdx.x], btot, __ATOMIC_RELAXED, __HIP_MEMORY_SCOPE_AGENT);
        __hip_atomic_store(&flags[blockIdx.x], 1, __ATOMIC_RELEASE, __HIP_MEMORY_SCOPE_AGENT);
    }
    __shared__ int s_off;
    if (tid < 64) {
        int contrib = 0;
        if (tid < blockIdx.x) {            // gridDim <= 64
            while (!__hip_atomic_load(&flags[tid], __ATOMIC_ACQUIRE, __HIP_MEMORY_SCOPE_AGENT))
                __builtin_amdgcn_s_sleep(1);
            contrib = __hip_atomic_load(&bsum[tid], __ATOMIC_RELAXED, __HIP_MEMORY_SCOPE_AGENT);
        }
        #pragma unroll
        for (int off = 32; off >= 1; off >>= 1) contrib += __shfl_xor(contrib, off);
        if (tid == 0) s_off = contrib;
    }
    if (blockIdx.x == 0 && tid == 0) row_ptr[n] = nE;
    __syncthreads();
    int woff = 0;
    #pragma unroll
    for (int w = 0; w < 4; ++w) woff += (w < wid) ? ws[w] : 0;
    int off = s_off + woff + (incl - tsum);
    #pragma unroll
    for (int k = 0; k < 4; ++k) {
        int idx = base + k;
        if (idx < n) row_ptr[idx] = off;
        off += v[k];
    }
}

// ---------------- scatter edges into CSR (no atomics; rank precomputed) ----------------
__global__ __launch_bounds__(256) void scatter_edges(const int* __restrict__ src,
                                                     const int* __restrict__ dst,
                                                     const int* __restrict__ row_ptr,
                                                     const int* __restrict__ rank,
                                                     int* __restrict__ ssrc, int nE) {
    int i = blockIdx.x * 256 + threadIdx.x;
    if (i < nE) {
        int d = dst[i];
        ssrc[row_ptr[d] + rank[i]] = src[i];
    }
}

// ---------------- mean aggregation: ONE WAVE PER NODE, 4 edge rows per instr ----------------
// lane = (q = lane>>4 edge-slot, rr = lane&15 channel-chunk). One vmem instr fetches
// 4 different edge rows x 256B. Unroll 2 -> 8 rows + 2 idx loads in flight.
// Final combine: 2 shfl_xor rounds (16, 32). No LDS -> max occupancy, 50K waves.
__global__ __launch_bounds__(256) void agg_mean(const ushort* __restrict__ feat,
                                                const int* __restrict__ row_ptr,
                                                const int* __restrict__ ssrc,
                                                ushort* __restrict__ out, int nNodes) {
    const int node = blockIdx.x * 4 + (threadIdx.x >> 6);
    const int lane = threadIdx.x & 63;
    if (node >= nNodes) return;
    const int q = lane >> 4, rr = lane & 15;
    const int beg = row_ptr[node];
    const int deg = row_ptr[node + 1] - beg;

    float a[8];
    #pragma unroll
    for (int e = 0; e < 8; ++e) a[e] = 0.f;

    const ushort* fb = feat + rr * 8;
    int j = 0;
    for (; j + 8 <= deg; j += 8) {
        int s0 = ssrc[beg + j + q];
        int s1 = ssrc[beg + j + 4 + q];
        bf16x8 v0 = *(const bf16x8*)(fb + (size_t)s0 * IN_CH);
        bf16x8 v1 = *(const bf16x8*)(fb + (size_t)s1 * IN_CH);
        #pragma unroll
        for (int e = 0; e < 8; ++e) a[e] += b2f((ushort)v0[e]);
        #pragma unroll
        for (int e = 0; e < 8; ++e) a[e] += b2f((ushort)v1[e]);
    }
    for (; j < deg; j += 4) {
        if (j + q < deg) {
            int s = ssrc[beg + j + q];
            bf16x8 v = *(const bf16x8*)(fb + (size_t)s * IN_CH);
            #pragma unroll
            for (int e = 0; e < 8; ++e) a[e] += b2f((ushort)v[e]);
        }
    }

    // combine 4 edge-slot groups
    #pragma unroll
    for (int e = 0; e < 8; ++e) {
        a[e] += __shfl_xor(a[e], 16);
        a[e] += __shfl_xor(a[e], 32);
    }

    if (q == 0) {
        float inv = 1.0f / fmaxf((float)deg, 1.0f);
        union { ushort u[8]; uint4 v; } p;
        #pragma unroll
        for (int e = 0; e < 8; ++e) p.u[e] = f2b(a[e] * inv);
        ((uint4*)(out + (size_t)node * IN_CH))[rr] = p.v;
    }
}

// ---------------- MFMA dual GEMM: out = act(A@Wl + bias + B@Wr) ----------------
// A,B: [nRows][128] bf16. WlT,WrT: [N][128] bf16 (pre-transposed). N = NT*16.
// 4 waves/block, 16 rows/wave, no LDS. Optional fused log_softmax (N must be 64).
template <int NT, bool RELU, bool OUTBF, bool LOGSM>
__global__ __launch_bounds__(256) void gemm_mfma(const ushort* __restrict__ A,
                                                 const ushort* __restrict__ B,
                                                 const ushort* __restrict__ WlT,
                                                 const ushort* __restrict__ WrT,
                                                 const float* __restrict__ bias,
                                                 void* __restrict__ outp, int nRows) {
    const int lane = threadIdx.x & 63;
    const int wave = threadIdx.x >> 6;
    const int m0 = blockIdx.x * 64 + wave * 16;
    const int r = lane & 15, g = lane >> 4;
    int row = m0 + r;
    if (row >= nRows) row = nRows - 1;           // clamp loads; stores masked
    const int kc = g * 8;

    f32x4 acc[NT];
    #pragma unroll
    for (int i = 0; i < NT; ++i) acc[i] = (f32x4){0.f, 0.f, 0.f, 0.f};

    #pragma unroll
    for (int mat = 0; mat < 2; ++mat) {
        const ushort* __restrict__ Ab = mat ? B : A;
        const ushort* __restrict__ Wb = mat ? WrT : WlT;
        const ushort* arow = Ab + (size_t)row * 128 + kc;
        #pragma unroll
        for (int k0 = 0; k0 < 128; k0 += 32) {
            bf16x8 af = *(const bf16x8*)(arow + k0);
            #pragma unroll
            for (int nt = 0; nt < NT; ++nt) {
                bf16x8 bfv = *(const bf16x8*)(Wb + (size_t)(nt * 16 + r) * 128 + k0 + kc);
                acc[nt] = __builtin_amdgcn_mfma_f32_16x16x32_bf16(af, bfv, acc[nt], 0, 0, 0);
            }
        }
    }

    constexpr int N = NT * 16;
    const int rbase = m0 + g * 4;

    float bv[NT];
    #pragma unroll
    for (int nt = 0; nt < NT; ++nt) bv[nt] = bias[nt * 16 + r];

    if (LOGSM) {
        #pragma unroll
        for (int q = 0; q < 4; ++q) {
            float m = -1e30f;
            #pragma unroll
            for (int nt = 0; nt < NT; ++nt) m = fmaxf(m, acc[nt][q] + bv[nt]);
            #pragma unroll
            for (int off = 8; off >= 1; off >>= 1) m = fmaxf(m, __shfl_xor(m, off));
            float s = 0.f;
            #pragma unroll
            for (int nt = 0; nt < NT; ++nt) s += expf(acc[nt][q] + bv[nt] - m);
            #pragma unroll
            for (int off = 8; off >= 1; off >>= 1) s += __shfl_xor(s, off);
            float lse = m + logf(s);
            if (rbase + q < nRows) {
                float* orow = (float*)outp + (size_t)(rbase + q) * N;
                #pragma unroll
                for (int nt = 0; nt < NT; ++nt)
                    orow[nt * 16 + r] = acc[nt][q] + bv[nt] - lse;
            }
        }
    } else {
        #pragma unroll
        for (int nt = 0; nt < NT; ++nt) {
            #pragma unroll
            for (int q = 0; q < 4; ++q) {
                if (rbase + q < nRows) {
                    float v = acc[nt][q] + bv[nt];
                    if (RELU) v = fmaxf(v, 0.f);
                    if (OUTBF)
                        ((ushort*)outp)[(size_t)(rbase + q) * N + nt * 16 + r] = f2b(v);
                    else
                        ((float*)outp)[(size_t)(rbase + q) * N + nt * 16 + r] = v;
                }
            }
        }
    }
}

extern "C" void kernel_launch(void* const* d_in, const int* in_sizes, int n_in,
                              void* d_out, int out_size, void* d_ws, size_t ws_size,
                              hipStream_t stream) {
    const float* x   = (const float*)d_in[0];
    const int* edges = (const int*)d_in[1];
    const float* Wl1 = (const float*)d_in[2];
    const float* bl1 = (const float*)d_in[3];
    const float* Wr1 = (const float*)d_in[4];
    const float* Wl2 = (const float*)d_in[5];
    const float* bl2 = (const float*)d_in[6];
    const float* Wr2 = (const float*)d_in[7];
    float* out = (float*)d_out;

    const int nN = in_sizes[0] / IN_CH;   // 50000
    const int nE = in_sizes[1] / 2;       // 600000

    // workspace carve
    ushort* xb   = (ushort*)d_ws;                 // nN*128 bf16
    ushort* aggb = xb + (size_t)nN * IN_CH;       // nN*128 bf16 (reused both layers)
    ushort* h    = aggb + (size_t)nN * IN_CH;     // nN*128 bf16
    ushort* WlT1 = h + (size_t)nN * IN_CH;        // 128*128
    ushort* WrT1 = WlT1 + 128 * 128;              // 128*128
    ushort* WlT2 = WrT1 + 128 * 128;              // 64*128
    ushort* WrT2 = WlT2 + 64 * 128;               // 64*128
    int* degI    = (int*)(WrT2 + 64 * 128);       // nN
    int* flags   = degI + nN;                     // 64 (zeroed with degI)
    int* row_ptr = flags + 64;                    // nN+1
    int* bsum    = row_ptr + (nN + 1);            // <=64
    int* ssrc    = bsum + 64;                     // nE
    int* rank    = ssrc + nE;                     // nE

    const int* esrc = edges;
    const int* edst = edges + nE;

    const int n8 = nN * IN_CH / 8;                // 800000
    const int nb = (nN + 1023) / 1024;            // 49 (<=64 required)

    prep<<<(n8 + 49152 + 255) / 256, 256, 0, stream>>>(x, xb, n8, degI, nN + 64,
                                                       Wl1, Wr1, Wl2, Wr2,
                                                       WlT1, WrT1, WlT2, WrT2);

    deg_hist<<<(nE + 255) / 256, 256, 0, stream>>>(edst, degI, rank, nE);
    scan_fused<<<nb, 256, 0, stream>>>(degI, bsum, flags, row_ptr, nN, nE);
    scatter_edges<<<(nE + 255) / 256, 256, 0, stream>>>(esrc, edst, row_ptr, rank, ssrc, nE);

    // layer 1
    agg_mean<<<(nN + 3) / 4, 256, 0, stream>>>(xb, row_ptr, ssrc, aggb, nN);
    gemm_mfma<8, true, true, false><<<(nN + 63) / 64, 256, 0, stream>>>(
        aggb, xb, WlT1, WrT1, bl1, h, nN);

    // layer 2 (+ fused log_softmax)
    agg_mean<<<(nN + 3) / 4, 256, 0, stream>>>(h, row_ptr, ssrc, aggb, nN);
    gemm_mfma<4, false, false, true><<<(nN + 63) / 64, 256, 0, stream>>>(
        aggb, h, WlT2, WrT2, bl2, out, nN);
}

// Round 8
// 238.113 us; speedup vs baseline: 1.0339x; 1.0001x over previous
//
#include <hip/hip_runtime.h>
#include <hip/hip_bf16.h>
#include <math.h>

#define IN_CH 128

typedef __attribute__((ext_vector_type(8))) short bf16x8;
typedef __attribute__((ext_vector_type(4))) float f32x4;

__device__ __forceinline__ ushort f2b(float f) {
    union { float f; uint u; } c; c.f = f;
    uint u = c.u + 0x7fff + ((c.u >> 16) & 1);   // RNE
    return (ushort)(u >> 16);
}
__device__ __forceinline__ float b2f(uint hi16) {
    union { uint u; float f; } c; c.u = hi16 << 16;
    return c.f;
}

// ---------------- fused prep: x->bf16, zero deg+flags, 4 weight transposes ----------------
__global__ __launch_bounds__(256) void prep(const float* __restrict__ x,
                                            ushort* __restrict__ xb, int n8,
                                            int* __restrict__ zbuf, int nz,
                                            const float* __restrict__ Wl1,
                                            const float* __restrict__ Wr1,
                                            const float* __restrict__ Wl2,
                                            const float* __restrict__ Wr2,
                                            ushort* __restrict__ WlT1,
                                            ushort* __restrict__ WrT1,
                                            ushort* __restrict__ WlT2,
                                            ushort* __restrict__ WrT2) {
    int i = blockIdx.x * 256 + threadIdx.x;
    if (i < nz) zbuf[i] = 0;
    if (i < n8) {
        float4 a = ((const float4*)x)[2 * i];
        float4 b = ((const float4*)x)[2 * i + 1];
        union { ushort u[8]; uint4 v; } p;
        p.u[0] = f2b(a.x); p.u[1] = f2b(a.y); p.u[2] = f2b(a.z); p.u[3] = f2b(a.w);
        p.u[4] = f2b(b.x); p.u[5] = f2b(b.y); p.u[6] = f2b(b.z); p.u[7] = f2b(b.w);
        ((uint4*)xb)[i] = p.v;
    } else {
        int w = i - n8;
        if (w < 2 * 16384 + 2 * 8192) {
            const float* W; ushort* Wt; int N, r;
            if (w < 16384)      { W = Wl1; Wt = WlT1; N = 128; r = w; }
            else if (w < 32768) { W = Wr1; Wt = WrT1; N = 128; r = w - 16384; }
            else if (w < 40960) { W = Wl2; Wt = WlT2; N = 64;  r = w - 32768; }
            else                { W = Wr2; Wt = WrT2; N = 64;  r = w - 40960; }
            int n = r / 128, k = r % 128;
            Wt[n * 128 + k] = f2b(W[(size_t)k * N + n]);
        }
    }
}

// ---------------- degree histogram + per-edge rank ----------------
__global__ __launch_bounds__(256) void deg_hist(const int* __restrict__ dst,
                                                int* __restrict__ deg,
                                                int* __restrict__ rank, int nE) {
    int i = blockIdx.x * 256 + threadIdx.x;
    if (i < nE) rank[i] = atomicAdd(&deg[dst[i]], 1);
}

// ---------------- single-pass exclusive scan (49 blocks, co-resident publish+spin) ----------------
__global__ __launch_bounds__(256) void scan_fused(const int* __restrict__ deg,
                                                  int* __restrict__ bsum,
                                                  int* __restrict__ flags,
                                                  int* __restrict__ row_ptr,
                                                  int n, int nE) {
    const int tid = threadIdx.x, lane = tid & 63, wid = tid >> 6;
    const int base = blockIdx.x * 1024 + tid * 4;
    int v[4];
    int tsum = 0;
    #pragma unroll
    for (int k = 0; k < 4; ++k) {
        int idx = base + k;
        v[k] = (idx < n) ? deg[idx] : 0;
        tsum += v[k];
    }
    int incl = tsum;
    #pragma unroll
    for (int off = 1; off < 64; off <<= 1) {
        int t = __shfl_up(incl, off);
        if (lane >= off) incl += t;
    }
    __shared__ int ws[4];
    if (lane == 63) ws[wid] = incl;
    __syncthreads();
    if (tid == 0) {
        int btot = ws[0] + ws[1] + ws[2] + ws[3];
        __hip_atomic_store(&bsum[blockIdx.x], btot, __ATOMIC_RELAXED, __HIP_MEMORY_SCOPE_AGENT);
        __hip_atomic_store(&flags[blockIdx.x], 1, __ATOMIC_RELEASE, __HIP_MEMORY_SCOPE_AGENT);
    }
    __shared__ int s_off;
    if (tid < 64) {
        int contrib = 0;
        if (tid < blockIdx.x) {            // gridDim <= 64
            while (!__hip_atomic_load(&flags[tid], __ATOMIC_ACQUIRE, __HIP_MEMORY_SCOPE_AGENT))
                __builtin_amdgcn_s_sleep(1);
            contrib = __hip_atomic_load(&bsum[tid], __ATOMIC_RELAXED, __HIP_MEMORY_SCOPE_AGENT);
        }
        #pragma unroll
        for (int off = 32; off >= 1; off >>= 1) contrib += __shfl_xor(contrib, off);
        if (tid == 0) s_off = contrib;
    }
    if (blockIdx.x == 0 && tid == 0) row_ptr[n] = nE;
    __syncthreads();
    int woff = 0;
    #pragma unroll
    for (int w = 0; w < 4; ++w) woff += (w < wid) ? ws[w] : 0;
    int off = s_off + woff + (incl - tsum);
    #pragma unroll
    for (int k = 0; k < 4; ++k) {
        int idx = base + k;
        if (idx < n) row_ptr[idx] = off;
        off += v[k];
    }
}

// ---------------- scatter edges into CSR (no atomics; rank precomputed) ----------------
__global__ __launch_bounds__(256) void scatter_edges(const int* __restrict__ src,
                                                     const int* __restrict__ dst,
                                                     const int* __restrict__ row_ptr,
                                                     const int* __restrict__ rank,
                                                     int* __restrict__ ssrc, int nE) {
    int i = blockIdx.x * 256 + threadIdx.x;
    if (i < nE) {
        int d = dst[i];
        ssrc[row_ptr[d] + rank[i]] = src[i];
    }
}

// ---------------- mean aggregation (layer 1): one wave per node, 256B rows ----------------
__global__ __launch_bounds__(256) void agg_mean(const ushort* __restrict__ feat,
                                                const int* __restrict__ row_ptr,
                                                const int* __restrict__ ssrc,
                                                ushort* __restrict__ out, int nNodes) {
    const int node = blockIdx.x * 4 + (threadIdx.x >> 6);
    const int lane = threadIdx.x & 63;
    if (node >= nNodes) return;
    const int q = lane >> 4, rr = lane & 15;
    const int beg = row_ptr[node];
    const int deg = row_ptr[node + 1] - beg;

    float a[8];
    #pragma unroll
    for (int e = 0; e < 8; ++e) a[e] = 0.f;

    const ushort* fb = feat + rr * 8;
    int j = 0;
    for (; j + 8 <= deg; j += 8) {
        int s0 = ssrc[beg + j + q];
        int s1 = ssrc[beg + j + 4 + q];
        bf16x8 v0 = *(const bf16x8*)(fb + (size_t)s0 * IN_CH);
        bf16x8 v1 = *(const bf16x8*)(fb + (size_t)s1 * IN_CH);
        #pragma unroll
        for (int e = 0; e < 8; ++e) a[e] += b2f((ushort)v0[e]);
        #pragma unroll
        for (int e = 0; e < 8; ++e) a[e] += b2f((ushort)v1[e]);
    }
    for (; j < deg; j += 4) {
        if (j + q < deg) {
            int s = ssrc[beg + j + q];
            bf16x8 v = *(const bf16x8*)(fb + (size_t)s * IN_CH);
            #pragma unroll
            for (int e = 0; e < 8; ++e) a[e] += b2f((ushort)v[e]);
        }
    }

    #pragma unroll
    for (int e = 0; e < 8; ++e) {
        a[e] += __shfl_xor(a[e], 16);
        a[e] += __shfl_xor(a[e], 32);
    }

    if (q == 0) {
        float inv = 1.0f / fmaxf((float)deg, 1.0f);
        union { ushort u[8]; uint4 v; } p;
        #pragma unroll
        for (int e = 0; e < 8; ++e) p.u[e] = f2b(a[e] * inv);
        ((uint4*)(out + (size_t)node * IN_CH))[rr] = p.v;
    }
}

// ---------------- MFMA dual GEMM (layer 1): h = relu(A@Wl + bias + B@Wr) ----------------
template <int NT, bool RELU, bool OUTBF>
__global__ __launch_bounds__(256) void gemm_mfma(const ushort* __restrict__ A,
                                                 const ushort* __restrict__ B,
                                                 const ushort* __restrict__ WlT,
                                                 const ushort* __restrict__ WrT,
                                                 const float* __restrict__ bias,
                                                 void* __restrict__ outp, int nRows) {
    const int lane = threadIdx.x & 63;
    const int wave = threadIdx.x >> 6;
    const int m0 = blockIdx.x * 64 + wave * 16;
    const int r = lane & 15, g = lane >> 4;
    int row = m0 + r;
    if (row >= nRows) row = nRows - 1;
    const int kc = g * 8;

    f32x4 acc[NT];
    #pragma unroll
    for (int i = 0; i < NT; ++i) acc[i] = (f32x4){0.f, 0.f, 0.f, 0.f};

    #pragma unroll
    for (int mat = 0; mat < 2; ++mat) {
        const ushort* __restrict__ Ab = mat ? B : A;
        const ushort* __restrict__ Wb = mat ? WrT : WlT;
        const ushort* arow = Ab + (size_t)row * 128 + kc;
        #pragma unroll
        for (int k0 = 0; k0 < 128; k0 += 32) {
            bf16x8 af = *(const bf16x8*)(arow + k0);
            #pragma unroll
            for (int nt = 0; nt < NT; ++nt) {
                bf16x8 bfv = *(const bf16x8*)(Wb + (size_t)(nt * 16 + r) * 128 + k0 + kc);
                acc[nt] = __builtin_amdgcn_mfma_f32_16x16x32_bf16(af, bfv, acc[nt], 0, 0, 0);
            }
        }
    }

    constexpr int N = NT * 16;
    const int rbase = m0 + g * 4;

    float bv[NT];
    #pragma unroll
    for (int nt = 0; nt < NT; ++nt) bv[nt] = bias[nt * 16 + r];

    #pragma unroll
    for (int nt = 0; nt < NT; ++nt) {
        #pragma unroll
        for (int q = 0; q < 4; ++q) {
            if (rbase + q < nRows) {
                float v = acc[nt][q] + bv[nt];
                if (RELU) v = fmaxf(v, 0.f);
                if (OUTBF)
                    ((ushort*)outp)[(size_t)(rbase + q) * N + nt * 16 + r] = f2b(v);
                else
                    ((float*)outp)[(size_t)(rbase + q) * N + nt * 16 + r] = v;
            }
        }
    }
}

// ---------------- layer-2 transform: y2 = bf16(h@Wl2), s2 = f32(h@Wr2), N=64 ----------------
__global__ __launch_bounds__(256) void gemm_dualout(const ushort* __restrict__ h,
                                                    const ushort* __restrict__ WlT,
                                                    const ushort* __restrict__ WrT,
                                                    ushort* __restrict__ y2,
                                                    float* __restrict__ s2, int nRows) {
    const int lane = threadIdx.x & 63;
    const int wave = threadIdx.x >> 6;
    const int m0 = blockIdx.x * 64 + wave * 16;
    const int r = lane & 15, g = lane >> 4;
    int row = m0 + r;
    if (row >= nRows) row = nRows - 1;
    const int kc = g * 8;

    f32x4 accl[4], accr[4];
    #pragma unroll
    for (int i = 0; i < 4; ++i) {
        accl[i] = (f32x4){0.f, 0.f, 0.f, 0.f};
        accr[i] = (f32x4){0.f, 0.f, 0.f, 0.f};
    }

    const ushort* arow = h + (size_t)row * 128 + kc;
    #pragma unroll
    for (int c = 0; c < 4; ++c) {
        bf16x8 af = *(const bf16x8*)(arow + c * 32);
        #pragma unroll
        for (int t = 0; t < 4; ++t) {
            bf16x8 wl = *(const bf16x8*)(WlT + (size_t)(t * 16 + r) * 128 + c * 32 + kc);
            accl[t] = __builtin_amdgcn_mfma_f32_16x16x32_bf16(af, wl, accl[t], 0, 0, 0);
        }
        #pragma unroll
        for (int t = 0; t < 4; ++t) {
            bf16x8 wr = *(const bf16x8*)(WrT + (size_t)(t * 16 + r) * 128 + c * 32 + kc);
            accr[t] = __builtin_amdgcn_mfma_f32_16x16x32_bf16(af, wr, accr[t], 0, 0, 0);
        }
    }

    const int rbase = m0 + g * 4;
    #pragma unroll
    for (int t = 0; t < 4; ++t) {
        #pragma unroll
        for (int q = 0; q < 4; ++q) {
            if (rbase + q < nRows) {
                y2[(size_t)(rbase + q) * 64 + t * 16 + r] = f2b(accl[t][q]);
                s2[(size_t)(rbase + q) * 64 + t * 16 + r] = accr[t][q];
            }
        }
    }
}

// ---------------- layer-2 final: out = log_softmax(mean_agg(y2) + s2 + bias) ----------------
// One wave per node. y2 rows are 128B: q=lane>>4 edge slot, rr=lane&15 covers
// channels 4rr..4rr+3 (uint2 = 8B). One vmem instr = 4 edge rows.
__global__ __launch_bounds__(256) void agg_final(const ushort* __restrict__ y2,
                                                 const float* __restrict__ s2,
                                                 const int* __restrict__ row_ptr,
                                                 const int* __restrict__ ssrc,
                                                 const float* __restrict__ bias,
                                                 float* __restrict__ out, int nNodes) {
    const int node = blockIdx.x * 4 + (threadIdx.x >> 6);
    const int lane = threadIdx.x & 63;
    if (node >= nNodes) return;
    const int q = lane >> 4, rr = lane & 15;
    const int beg = row_ptr[node];
    const int deg = row_ptr[node + 1] - beg;

    float a[4] = {0.f, 0.f, 0.f, 0.f};
    const ushort* yb = y2 + rr * 4;

    #define ACC(vv) { a[0] += b2f((vv).x & 0xffffu); a[1] += b2f((vv).x >> 16); \
                      a[2] += b2f((vv).y & 0xffffu); a[3] += b2f((vv).y >> 16); }
    int j = 0;
    for (; j + 8 <= deg; j += 8) {
        int s0 = ssrc[beg + j + q];
        int s1 = ssrc[beg + j + 4 + q];
        uint2 v0 = *(const uint2*)(yb + (size_t)s0 * 64);
        uint2 v1 = *(const uint2*)(yb + (size_t)s1 * 64);
        ACC(v0); ACC(v1);
    }
    for (; j < deg; j += 4) {
        if (j + q < deg) {
            int s = ssrc[beg + j + q];
            uint2 v = *(const uint2*)(yb + (size_t)s * 64);
            ACC(v);
        }
    }
    #undef ACC

    #pragma unroll
    for (int e = 0; e < 4; ++e) {
        a[e] += __shfl_xor(a[e], 16);
        a[e] += __shfl_xor(a[e], 32);
    }

    if (q == 0) {
        float inv = 1.0f / fmaxf((float)deg, 1.0f);
        float4 sv = ((const float4*)(s2 + (size_t)node * 64))[rr];
        float4 bv = ((const float4*)bias)[rr];
        float v0 = a[0] * inv + sv.x + bv.x;
        float v1 = a[1] * inv + sv.y + bv.y;
        float v2 = a[2] * inv + sv.z + bv.z;
        float v3 = a[3] * inv + sv.w + bv.w;
        float m = fmaxf(fmaxf(v0, v1), fmaxf(v2, v3));
        #pragma unroll
        for (int off = 8; off >= 1; off >>= 1) m = fmaxf(m, __shfl_xor(m, off));
        float s = expf(v0 - m) + expf(v1 - m) + expf(v2 - m) + expf(v3 - m);
        #pragma unroll
        for (int off = 8; off >= 1; off >>= 1) s += __shfl_xor(s, off);
        float lse = m + logf(s);
        float4 o = {v0 - lse, v1 - lse, v2 - lse, v3 - lse};
        ((float4*)(out + (size_t)node * 64))[rr] = o;
    }
}

extern "C" void kernel_launch(void* const* d_in, const int* in_sizes, int n_in,
                              void* d_out, int out_size, void* d_ws, size_t ws_size,
                              hipStream_t stream) {
    const float* x   = (const float*)d_in[0];
    const int* edges = (const int*)d_in[1];
    const float* Wl1 = (const float*)d_in[2];
    const float* bl1 = (const float*)d_in[3];
    const float* Wr1 = (const float*)d_in[4];
    const float* Wl2 = (const float*)d_in[5];
    const float* bl2 = (const float*)d_in[6];
    const float* Wr2 = (const float*)d_in[7];
    float* out = (float*)d_out;

    const int nN = in_sizes[0] / IN_CH;   // 50000
    const int nE = in_sizes[1] / 2;       // 600000

    // workspace carve
    ushort* xb   = (ushort*)d_ws;                 // nN*128 bf16
    ushort* aggb = xb + (size_t)nN * IN_CH;       // nN*128 bf16 (layer-1 agg)
    ushort* h    = aggb + (size_t)nN * IN_CH;     // nN*128 bf16
    ushort* y2   = h + (size_t)nN * IN_CH;        // nN*64 bf16
    float*  s2   = (float*)(y2 + (size_t)nN * 64);// nN*64 f32
    ushort* WlT1 = (ushort*)(s2 + (size_t)nN * 64); // 128*128
    ushort* WrT1 = WlT1 + 128 * 128;              // 128*128
    ushort* WlT2 = WrT1 + 128 * 128;              // 64*128
    ushort* WrT2 = WlT2 + 64 * 128;               // 64*128
    int* degI    = (int*)(WrT2 + 64 * 128);       // nN
    int* flags   = degI + nN;                     // 64 (zeroed with degI)
    int* row_ptr = flags + 64;                    // nN+1
    int* bsum    = row_ptr + (nN + 1);            // <=64
    int* ssrc    = bsum + 64;                     // nE
    int* rank    = ssrc + nE;                     // nE

    const int* esrc = edges;
    const int* edst = edges + nE;

    const int n8 = nN * IN_CH / 8;                // 800000
    const int nb = (nN + 1023) / 1024;            // 49 (<=64 required)

    prep<<<(n8 + 49152 + 255) / 256, 256, 0, stream>>>(x, xb, n8, degI, nN + 64,
                                                       Wl1, Wr1, Wl2, Wr2,
                                                       WlT1, WrT1, WlT2, WrT2);

    deg_hist<<<(nE + 255) / 256, 256, 0, stream>>>(edst, degI, rank, nE);
    scan_fused<<<nb, 256, 0, stream>>>(degI, bsum, flags, row_ptr, nN, nE);
    scatter_edges<<<(nE + 255) / 256, 256, 0, stream>>>(esrc, edst, row_ptr, rank, ssrc, nE);

    // layer 1
    agg_mean<<<(nN + 3) / 4, 256, 0, stream>>>(xb, row_ptr, ssrc, aggb, nN);
    gemm_mfma<8, true, true><<<(nN + 63) / 64, 256, 0, stream>>>(
        aggb, xb, WlT1, WrT1, bl1, h, nN);

    // layer 2: transform first (linearity of mean-agg), then 128B-row gather + epilogue
    gemm_dualout<<<(nN + 63) / 64, 256, 0, stream>>>(h, WlT2, WrT2, y2, s2, nN);
    agg_final<<<(nN + 3) / 4, 256, 0, stream>>>(y2, s2, row_ptr, ssrc, bl2, out, nN);
}

// Round 11
// 237.076 us; speedup vs baseline: 1.0384x; 1.0044x over previous
//
#include <hip/hip_runtime.h>
#include <hip/hip_bf16.h>
#include <math.h>

#define IN_CH 128

typedef __attribute__((ext_vector_type(8))) short bf16x8;
typedef __attribute__((ext_vector_type(4))) float f32x4;

__device__ __forceinline__ ushort f2b(float f) {
    union { float f; uint u; } c; c.f = f;
    uint u = c.u + 0x7fff + ((c.u >> 16) & 1);   // RNE
    return (ushort)(u >> 16);
}
__device__ __forceinline__ float b2f(uint hi16) {
    union { uint u; float f; } c; c.u = hi16 << 16;
    return c.f;
}

// ---------------- fused prep: x->bf16, zero deg+flags, 4 weight transposes ----------------
__global__ __launch_bounds__(256) void prep(const float* __restrict__ x,
                                            ushort* __restrict__ xb, int n8,
                                            int* __restrict__ zbuf, int nz,
                                            const float* __restrict__ Wl1,
                                            const float* __restrict__ Wr1,
                                            const float* __restrict__ Wl2,
                                            const float* __restrict__ Wr2,
                                            ushort* __restrict__ WlT1,
                                            ushort* __restrict__ WrT1,
                                            ushort* __restrict__ WlT2,
                                            ushort* __restrict__ WrT2) {
    int i = blockIdx.x * 256 + threadIdx.x;
    if (i < nz) zbuf[i] = 0;
    if (i < n8) {
        float4 a = ((const float4*)x)[2 * i];
        float4 b = ((const float4*)x)[2 * i + 1];
        union { ushort u[8]; uint4 v; } p;
        p.u[0] = f2b(a.x); p.u[1] = f2b(a.y); p.u[2] = f2b(a.z); p.u[3] = f2b(a.w);
        p.u[4] = f2b(b.x); p.u[5] = f2b(b.y); p.u[6] = f2b(b.z); p.u[7] = f2b(b.w);
        ((uint4*)xb)[i] = p.v;
    } else {
        int w = i - n8;
        if (w < 2 * 16384 + 2 * 8192) {
            const float* W; ushort* Wt; int N, r;
            if (w < 16384)      { W = Wl1; Wt = WlT1; N = 128; r = w; }
            else if (w < 32768) { W = Wr1; Wt = WrT1; N = 128; r = w - 16384; }
            else if (w < 40960) { W = Wl2; Wt = WlT2; N = 64;  r = w - 32768; }
            else                { W = Wr2; Wt = WrT2; N = 64;  r = w - 40960; }
            int n = r / 128, k = r % 128;
            Wt[n * 128 + k] = f2b(W[(size_t)k * N + n]);
        }
    }
}

// ---------------- degree histogram + per-edge rank ----------------
__global__ __launch_bounds__(256) void deg_hist(const int* __restrict__ dst,
                                                int* __restrict__ deg,
                                                int* __restrict__ rank, int nE) {
    int i = blockIdx.x * 256 + threadIdx.x;
    if (i < nE) rank[i] = atomicAdd(&deg[dst[i]], 1);
}

// ---------------- single-pass exclusive scan (49 blocks, co-resident publish+spin) ----------------
__global__ __launch_bounds__(256) void scan_fused(const int* __restrict__ deg,
                                                  int* __restrict__ bsum,
                                                  int* __restrict__ flags,
                                                  int* __restrict__ row_ptr,
                                                  int n, int nE) {
    const int tid = threadIdx.x, lane = tid & 63, wid = tid >> 6;
    const int base = blockIdx.x * 1024 + tid * 4;
    int v[4];
    int tsum = 0;
    #pragma unroll
    for (int k = 0; k < 4; ++k) {
        int idx = base + k;
        v[k] = (idx < n) ? deg[idx] : 0;
        tsum += v[k];
    }
    int incl = tsum;
    #pragma unroll
    for (int off = 1; off < 64; off <<= 1) {
        int t = __shfl_up(incl, off);
        if (lane >= off) incl += t;
    }
    __shared__ int ws[4];
    if (lane == 63) ws[wid] = incl;
    __syncthreads();
    if (tid == 0) {
        int btot = ws[0] + ws[1] + ws[2] + ws[3];
        __hip_atomic_store(&bsum[blockIdx.x], btot, __ATOMIC_RELAXED, __HIP_MEMORY_SCOPE_AGENT);
        __hip_atomic_store(&flags[blockIdx.x], 1, __ATOMIC_RELEASE, __HIP_MEMORY_SCOPE_AGENT);
    }
    __shared__ int s_off;
    if (tid < 64) {
        int contrib = 0;
        if (tid < blockIdx.x) {            // gridDim <= 64
            while (!__hip_atomic_load(&flags[tid], __ATOMIC_ACQUIRE, __HIP_MEMORY_SCOPE_AGENT))
                __builtin_amdgcn_s_sleep(1);
            contrib = __hip_atomic_load(&bsum[tid], __ATOMIC_RELAXED, __HIP_MEMORY_SCOPE_AGENT);
        }
        #pragma unroll
        for (int off = 32; off >= 1; off >>= 1) contrib += __shfl_xor(contrib, off);
        if (tid == 0) s_off = contrib;
    }
    if (blockIdx.x == 0 && tid == 0) row_ptr[n] = nE;
    __syncthreads();
    int woff = 0;
    #pragma unroll
    for (int w = 0; w < 4; ++w) woff += (w < wid) ? ws[w] : 0;
    int off = s_off + woff + (incl - tsum);
    #pragma unroll
    for (int k = 0; k < 4; ++k) {
        int idx = base + k;
        if (idx < n) row_ptr[idx] = off;
        off += v[k];
    }
}

// ---------------- scatter edges into CSR (no atomics; rank precomputed) ----------------
__global__ __launch_bounds__(256) void scatter_edges(const int* __restrict__ src,
                                                     const int* __restrict__ dst,
                                                     const int* __restrict__ row_ptr,
                                                     const int* __restrict__ rank,
                                                     int* __restrict__ ssrc, int nE) {
    int i = blockIdx.x * 256 + threadIdx.x;
    if (i < nE) {
        int d = dst[i];
        ssrc[row_ptr[d] + rank[i]] = src[i];
    }
}

// ---------------- mean aggregation (layer 1): one wave per node ----------------
// Main loop: indices prefetched once (coalesced ssrc[beg+lane]) and distributed
// via UNIFORM shfl (loop bound nf8 is wave-uniform, multiple of 8 -> no divergent
// shfl). Tail + deg>64 fallback: direct ssrc loads (R8-identical).
__global__ __launch_bounds__(256) void agg_mean(const ushort* __restrict__ feat,
                                                const int* __restrict__ row_ptr,
                                                const int* __restrict__ ssrc,
                                                ushort* __restrict__ out, int nNodes) {
    const int node = blockIdx.x * 4 + (threadIdx.x >> 6);
    const int lane = threadIdx.x & 63;
    if (node >= nNodes) return;
    const int q = lane >> 4, rr = lane & 15;
    const int beg = row_ptr[node];
    const int deg = row_ptr[node + 1] - beg;   // wave-uniform

    float a[8];
    #pragma unroll
    for (int e = 0; e < 8; ++e) a[e] = 0.f;

    const ushort* fb = feat + rr * 8;
    int idx = 0;
    if (lane < deg) idx = ssrc[beg + lane];
    const int nf8 = min(deg, 64) & ~7;         // wave-uniform, multiple of 8

    int j = 0;
    for (; j < nf8; j += 8) {                  // uniform execution: shfl safe
        int s0 = __shfl(idx, j + q);
        int s1 = __shfl(idx, j + 4 + q);
        bf16x8 v0 = *(const bf16x8*)(fb + (size_t)s0 * IN_CH);
        bf16x8 v1 = *(const bf16x8*)(fb + (size_t)s1 * IN_CH);
        #pragma unroll
        for (int e = 0; e < 8; ++e) a[e] += b2f((ushort)v0[e]);
        #pragma unroll
        for (int e = 0; e < 8; ++e) a[e] += b2f((ushort)v1[e]);
    }
    for (; j < deg; j += 4) {                  // tail: direct loads, no shfl
        if (j + q < deg) {
            int s = ssrc[beg + j + q];
            bf16x8 v = *(const bf16x8*)(fb + (size_t)s * IN_CH);
            #pragma unroll
            for (int e = 0; e < 8; ++e) a[e] += b2f((ushort)v[e]);
        }
    }

    #pragma unroll
    for (int e = 0; e < 8; ++e) {
        a[e] += __shfl_xor(a[e], 16);
        a[e] += __shfl_xor(a[e], 32);
    }

    if (q == 0) {
        float inv = 1.0f / fmaxf((float)deg, 1.0f);
        union { ushort u[8]; uint4 v; } p;
        #pragma unroll
        for (int e = 0; e < 8; ++e) p.u[e] = f2b(a[e] * inv);
        ((uint4*)(out + (size_t)node * IN_CH))[rr] = p.v;
    }
}

// ---------------- MFMA dual GEMM (layer 1): h = relu(A@Wl + bias + B@Wr) ----------------
template <int NT, bool RELU, bool OUTBF>
__global__ __launch_bounds__(256) void gemm_mfma(const ushort* __restrict__ A,
                                                 const ushort* __restrict__ B,
                                                 const ushort* __restrict__ WlT,
                                                 const ushort* __restrict__ WrT,
                                                 const float* __restrict__ bias,
                                                 void* __restrict__ outp, int nRows) {
    const int lane = threadIdx.x & 63;
    const int wave = threadIdx.x >> 6;
    const int m0 = blockIdx.x * 64 + wave * 16;
    const int r = lane & 15, g = lane >> 4;
    int row = m0 + r;
    if (row >= nRows) row = nRows - 1;
    const int kc = g * 8;

    f32x4 acc[NT];
    #pragma unroll
    for (int i = 0; i < NT; ++i) acc[i] = (f32x4){0.f, 0.f, 0.f, 0.f};

    #pragma unroll
    for (int mat = 0; mat < 2; ++mat) {
        const ushort* __restrict__ Ab = mat ? B : A;
        const ushort* __restrict__ Wb = mat ? WrT : WlT;
        const ushort* arow = Ab + (size_t)row * 128 + kc;
        #pragma unroll
        for (int k0 = 0; k0 < 128; k0 += 32) {
            bf16x8 af = *(const bf16x8*)(arow + k0);
            #pragma unroll
            for (int nt = 0; nt < NT; ++nt) {
                bf16x8 bfv = *(const bf16x8*)(Wb + (size_t)(nt * 16 + r) * 128 + k0 + kc);
                acc[nt] = __builtin_amdgcn_mfma_f32_16x16x32_bf16(af, bfv, acc[nt], 0, 0, 0);
            }
        }
    }

    constexpr int N = NT * 16;
    const int rbase = m0 + g * 4;

    float bv[NT];
    #pragma unroll
    for (int nt = 0; nt < NT; ++nt) bv[nt] = bias[nt * 16 + r];

    #pragma unroll
    for (int nt = 0; nt < NT; ++nt) {
        #pragma unroll
        for (int q = 0; q < 4; ++q) {
            if (rbase + q < nRows) {
                float v = acc[nt][q] + bv[nt];
                if (RELU) v = fmaxf(v, 0.f);
                if (OUTBF)
                    ((ushort*)outp)[(size_t)(rbase + q) * N + nt * 16 + r] = f2b(v);
                else
                    ((float*)outp)[(size_t)(rbase + q) * N + nt * 16 + r] = v;
            }
        }
    }
}

// ---------------- layer-2 transform: y2 = bf16(h@Wl2), s2 = f32(h@Wr2), N=64 ----------------
__global__ __launch_bounds__(256) void gemm_dualout(const ushort* __restrict__ h,
                                                    const ushort* __restrict__ WlT,
                                                    const ushort* __restrict__ WrT,
                                                    ushort* __restrict__ y2,
                                                    float* __restrict__ s2, int nRows) {
    const int lane = threadIdx.x & 63;
    const int wave = threadIdx.x >> 6;
    const int m0 = blockIdx.x * 64 + wave * 16;
    const int r = lane & 15, g = lane >> 4;
    int row = m0 + r;
    if (row >= nRows) row = nRows - 1;
    const int kc = g * 8;

    f32x4 accl[4], accr[4];
    #pragma unroll
    for (int i = 0; i < 4; ++i) {
        accl[i] = (f32x4){0.f, 0.f, 0.f, 0.f};
        accr[i] = (f32x4){0.f, 0.f, 0.f, 0.f};
    }

    const ushort* arow = h + (size_t)row * 128 + kc;
    #pragma unroll
    for (int c = 0; c < 4; ++c) {
        bf16x8 af = *(const bf16x8*)(arow + c * 32);
        #pragma unroll
        for (int t = 0; t < 4; ++t) {
            bf16x8 wl = *(const bf16x8*)(WlT + (size_t)(t * 16 + r) * 128 + c * 32 + kc);
            accl[t] = __builtin_amdgcn_mfma_f32_16x16x32_bf16(af, wl, accl[t], 0, 0, 0);
        }
        #pragma unroll
        for (int t = 0; t < 4; ++t) {
            bf16x8 wr = *(const bf16x8*)(WrT + (size_t)(t * 16 + r) * 128 + c * 32 + kc);
            accr[t] = __builtin_amdgcn_mfma_f32_16x16x32_bf16(af, wr, accr[t], 0, 0, 0);
        }
    }

    const int rbase = m0 + g * 4;
    #pragma unroll
    for (int t = 0; t < 4; ++t) {
        #pragma unroll
        for (int q = 0; q < 4; ++q) {
            if (rbase + q < nRows) {
                y2[(size_t)(rbase + q) * 64 + t * 16 + r] = f2b(accl[t][q]);
                s2[(size_t)(rbase + q) * 64 + t * 16 + r] = accr[t][q];
            }
        }
    }
}

// ---------------- layer-2 final: out = log_softmax(mean_agg(y2) + s2 + bias) ----------------
__global__ __launch_bounds__(256) void agg_final(const ushort* __restrict__ y2,
                                                 const float* __restrict__ s2,
                                                 const int* __restrict__ row_ptr,
                                                 const int* __restrict__ ssrc,
                                                 const float* __restrict__ bias,
                                                 float* __restrict__ out, int nNodes) {
    const int node = blockIdx.x * 4 + (threadIdx.x >> 6);
    const int lane = threadIdx.x & 63;
    if (node >= nNodes) return;
    const int q = lane >> 4, rr = lane & 15;
    const int beg = row_ptr[node];
    const int deg = row_ptr[node + 1] - beg;   // wave-uniform

    float a[4] = {0.f, 0.f, 0.f, 0.f};
    const ushort* yb = y2 + rr * 4;
    int idx = 0;
    if (lane < deg) idx = ssrc[beg + lane];
    const int nf8 = min(deg, 64) & ~7;         // wave-uniform, multiple of 8

    #define ACC(vv) { a[0] += b2f((vv).x & 0xffffu); a[1] += b2f((vv).x >> 16); \
                      a[2] += b2f((vv).y & 0xffffu); a[3] += b2f((vv).y >> 16); }
    int j = 0;
    for (; j < nf8; j += 8) {                  // uniform execution: shfl safe
        int s0 = __shfl(idx, j + q);
        int s1 = __shfl(idx, j + 4 + q);
        uint2 v0 = *(const uint2*)(yb + (size_t)s0 * 64);
        uint2 v1 = *(const uint2*)(yb + (size_t)s1 * 64);
        ACC(v0); ACC(v1);
    }
    for (; j < deg; j += 4) {                  // tail: direct loads, no shfl
        if (j + q < deg) {
            int s = ssrc[beg + j + q];
            uint2 v = *(const uint2*)(yb + (size_t)s * 64);
            ACC(v);
        }
    }
    #undef ACC

    #pragma unroll
    for (int e = 0; e < 4; ++e) {
        a[e] += __shfl_xor(a[e], 16);
        a[e] += __shfl_xor(a[e], 32);
    }

    if (q == 0) {
        float inv = 1.0f / fmaxf((float)deg, 1.0f);
        float4 sv = ((const float4*)(s2 + (size_t)node * 64))[rr];
        float4 bv = ((const float4*)bias)[rr];
        float v0 = a[0] * inv + sv.x + bv.x;
        float v1 = a[1] * inv + sv.y + bv.y;
        float v2 = a[2] * inv + sv.z + bv.z;
        float v3 = a[3] * inv + sv.w + bv.w;
        float m = fmaxf(fmaxf(v0, v1), fmaxf(v2, v3));
        #pragma unroll
        for (int off = 8; off >= 1; off >>= 1) m = fmaxf(m, __shfl_xor(m, off));
        float s = expf(v0 - m) + expf(v1 - m) + expf(v2 - m) + expf(v3 - m);
        #pragma unroll
        for (int off = 8; off >= 1; off >>= 1) s += __shfl_xor(s, off);
        float lse = m + logf(s);
        float4 o = {v0 - lse, v1 - lse, v2 - lse, v3 - lse};
        ((float4*)(out + (size_t)node * 64))[rr] = o;
    }
}

extern "C" void kernel_launch(void* const* d_in, const int* in_sizes, int n_in,
                              void* d_out, int out_size, void* d_ws, size_t ws_size,
                              hipStream_t stream) {
    const float* x   = (const float*)d_in[0];
    const int* edges = (const int*)d_in[1];
    const float* Wl1 = (const float*)d_in[2];
    const float* bl1 = (const float*)d_in[3];
    const float* Wr1 = (const float*)d_in[4];
    const float* Wl2 = (const float*)d_in[5];
    const float* bl2 = (const float*)d_in[6];
    const float* Wr2 = (const float*)d_in[7];
    float* out = (float*)d_out;

    const int nN = in_sizes[0] / IN_CH;   // 50000
    const int nE = in_sizes[1] / 2;       // 600000

    // workspace carve
    ushort* xb   = (ushort*)d_ws;                 // nN*128 bf16
    ushort* aggb = xb + (size_t)nN * IN_CH;       // nN*128 bf16 (layer-1 agg)
    ushort* h    = aggb + (size_t)nN * IN_CH;     // nN*128 bf16
    ushort* y2   = h + (size_t)nN * IN_CH;        // nN*64 bf16
    float*  s2   = (float*)(y2 + (size_t)nN * 64);// nN*64 f32
    ushort* WlT1 = (ushort*)(s2 + (size_t)nN * 64); // 128*128
    ushort* WrT1 = WlT1 + 128 * 128;              // 128*128
    ushort* WlT2 = WrT1 + 128 * 128;              // 64*128
    ushort* WrT2 = WlT2 + 64 * 128;               // 64*128
    int* degI    = (int*)(WrT2 + 64 * 128);       // nN
    int* flags   = degI + nN;                     // 64 (zeroed with degI)
    int* row_ptr = flags + 64;                    // nN+1
    int* bsum    = row_ptr + (nN + 1);            // <=64
    int* ssrc    = bsum + 64;                     // nE
    int* rank    = ssrc + nE;                     // nE

    const int* esrc = edges;
    const int* edst = edges + nE;

    const int n8 = nN * IN_CH / 8;                // 800000
    const int nb = (nN + 1023) / 1024;            // 49 (<=64 required)

    prep<<<(n8 + 49152 + 255) / 256, 256, 0, stream>>>(x, xb, n8, degI, nN + 64,
                                                       Wl1, Wr1, Wl2, Wr2,
                                                       WlT1, WrT1, WlT2, WrT2);

    deg_hist<<<(nE + 255) / 256, 256, 0, stream>>>(edst, degI, rank, nE);
    scan_fused<<<nb, 256, 0, stream>>>(degI, bsum, flags, row_ptr, nN, nE);
    scatter_edges<<<(nE + 255) / 256, 256, 0, stream>>>(esrc, edst, row_ptr, rank, ssrc, nE);

    // layer 1
    agg_mean<<<(nN + 3) / 4, 256, 0, stream>>>(xb, row_ptr, ssrc, aggb, nN);
    gemm_mfma<8, true, true><<<(nN + 63) / 64, 256, 0, stream>>>(
        aggb, xb, WlT1, WrT1, bl1, h, nN);

    // layer 2: transform first (linearity of mean-agg), then 128B-row gather + epilogue
    gemm_dualout<<<(nN + 63) / 64, 256, 0, stream>>>(h, WlT2, WrT2, y2, s2, nN);
    agg_final<<<(nN + 3) / 4, 256, 0, stream>>>(y2, s2, row_ptr, ssrc, bl2, out, nN);
}

// Round 12
// 230.015 us; speedup vs baseline: 1.0703x; 1.0307x over previous
//
#include <hip/hip_runtime.h>
#include <hip/hip_bf16.h>
#include <math.h>

#define IN_CH 128

typedef __attribute__((ext_vector_type(8))) short bf16x8;
typedef __attribute__((ext_vector_type(4))) float f32x4;

__device__ __forceinline__ ushort f2b(float f) {
    union { float f; uint u; } c; c.f = f;
    uint u = c.u + 0x7fff + ((c.u >> 16) & 1);   // RNE
    return (ushort)(u >> 16);
}
__device__ __forceinline__ float b2f(uint hi16) {
    union { uint u; float f; } c; c.u = hi16 << 16;
    return c.f;
}

// ---------------- fused prep: x->bf16, 4 weight transposes, edge histogram ----------------
// degI/flags zeroed beforehand via hipMemsetAsync (avoids zero-vs-atomic race).
__global__ __launch_bounds__(256) void prep_hist(const float* __restrict__ x,
                                                 ushort* __restrict__ xb, int n8,
                                                 const float* __restrict__ Wl1,
                                                 const float* __restrict__ Wr1,
                                                 const float* __restrict__ Wl2,
                                                 const float* __restrict__ Wr2,
                                                 ushort* __restrict__ WlT1,
                                                 ushort* __restrict__ WrT1,
                                                 ushort* __restrict__ WlT2,
                                                 ushort* __restrict__ WrT2,
                                                 const int* __restrict__ edst,
                                                 int* __restrict__ degI,
                                                 int* __restrict__ rank, int nE) {
    int i = blockIdx.x * 256 + threadIdx.x;
    if (i < nE) rank[i] = atomicAdd(&degI[edst[i]], 1);
    if (i < n8) {
        float4 a = ((const float4*)x)[2 * i];
        float4 b = ((const float4*)x)[2 * i + 1];
        union { ushort u[8]; uint4 v; } p;
        p.u[0] = f2b(a.x); p.u[1] = f2b(a.y); p.u[2] = f2b(a.z); p.u[3] = f2b(a.w);
        p.u[4] = f2b(b.x); p.u[5] = f2b(b.y); p.u[6] = f2b(b.z); p.u[7] = f2b(b.w);
        ((uint4*)xb)[i] = p.v;
    } else {
        int w = i - n8;
        if (w < 2 * 16384 + 2 * 8192) {
            const float* W; ushort* Wt; int N, r;
            if (w < 16384)      { W = Wl1; Wt = WlT1; N = 128; r = w; }
            else if (w < 32768) { W = Wr1; Wt = WrT1; N = 128; r = w - 16384; }
            else if (w < 40960) { W = Wl2; Wt = WlT2; N = 64;  r = w - 32768; }
            else                { W = Wr2; Wt = WrT2; N = 64;  r = w - 40960; }
            int n = r / 128, k = r % 128;
            Wt[n * 128 + k] = f2b(W[(size_t)k * N + n]);
        }
    }
}

// ---------------- single-pass exclusive scan (49 blocks, co-resident publish+spin) ----------------
__global__ __launch_bounds__(256) void scan_fused(const int* __restrict__ deg,
                                                  int* __restrict__ bsum,
                                                  int* __restrict__ flags,
                                                  int* __restrict__ row_ptr,
                                                  int n, int nE) {
    const int tid = threadIdx.x, lane = tid & 63, wid = tid >> 6;
    const int base = blockIdx.x * 1024 + tid * 4;
    int v[4];
    int tsum = 0;
    #pragma unroll
    for (int k = 0; k < 4; ++k) {
        int idx = base + k;
        v[k] = (idx < n) ? deg[idx] : 0;
        tsum += v[k];
    }
    int incl = tsum;
    #pragma unroll
    for (int off = 1; off < 64; off <<= 1) {
        int t = __shfl_up(incl, off);
        if (lane >= off) incl += t;
    }
    __shared__ int ws[4];
    if (lane == 63) ws[wid] = incl;
    __syncthreads();
    if (tid == 0) {
        int btot = ws[0] + ws[1] + ws[2] + ws[3];
        __hip_atomic_store(&bsum[blockIdx.x], btot, __ATOMIC_RELAXED, __HIP_MEMORY_SCOPE_AGENT);
        __hip_atomic_store(&flags[blockIdx.x], 1, __ATOMIC_RELEASE, __HIP_MEMORY_SCOPE_AGENT);
    }
    __shared__ int s_off;
    if (tid < 64) {
        int contrib = 0;
        if (tid < blockIdx.x) {            // gridDim <= 64
            while (!__hip_atomic_load(&flags[tid], __ATOMIC_ACQUIRE, __HIP_MEMORY_SCOPE_AGENT))
                __builtin_amdgcn_s_sleep(1);
            contrib = __hip_atomic_load(&bsum[tid], __ATOMIC_RELAXED, __HIP_MEMORY_SCOPE_AGENT);
        }
        #pragma unroll
        for (int off = 32; off >= 1; off >>= 1) contrib += __shfl_xor(contrib, off);
        if (tid == 0) s_off = contrib;
    }
    if (blockIdx.x == 0 && tid == 0) row_ptr[n] = nE;
    __syncthreads();
    int woff = 0;
    #pragma unroll
    for (int w = 0; w < 4; ++w) woff += (w < wid) ? ws[w] : 0;
    int off = s_off + woff + (incl - tsum);
    #pragma unroll
    for (int k = 0; k < 4; ++k) {
        int idx = base + k;
        if (idx < n) row_ptr[idx] = off;
        off += v[k];
    }
}

// ---------------- scatter edges into CSR (no atomics; rank precomputed) ----------------
__global__ __launch_bounds__(256) void scatter_edges(const int* __restrict__ src,
                                                     const int* __restrict__ dst,
                                                     const int* __restrict__ row_ptr,
                                                     const int* __restrict__ rank,
                                                     int* __restrict__ ssrc, int nE) {
    int i = blockIdx.x * 256 + threadIdx.x;
    if (i < nE) {
        int d = dst[i];
        ssrc[row_ptr[d] + rank[i]] = src[i];
    }
}

// ---------------- mean aggregation (layer 1): one wave per node, uniform idx-prefetch ----------------
__global__ __launch_bounds__(256) void agg_mean(const ushort* __restrict__ feat,
                                                const int* __restrict__ row_ptr,
                                                const int* __restrict__ ssrc,
                                                ushort* __restrict__ out, int nNodes) {
    const int node = blockIdx.x * 4 + (threadIdx.x >> 6);
    const int lane = threadIdx.x & 63;
    if (node >= nNodes) return;
    const int q = lane >> 4, rr = lane & 15;
    const int beg = row_ptr[node];
    const int deg = row_ptr[node + 1] - beg;   // wave-uniform

    float a[8];
    #pragma unroll
    for (int e = 0; e < 8; ++e) a[e] = 0.f;

    const ushort* fb = feat + rr * 8;
    int idx = 0;
    if (lane < deg) idx = ssrc[beg + lane];
    const int nf8 = min(deg, 64) & ~7;         // wave-uniform, multiple of 8

    int j = 0;
    for (; j < nf8; j += 8) {                  // uniform execution: shfl safe
        int s0 = __shfl(idx, j + q);
        int s1 = __shfl(idx, j + 4 + q);
        bf16x8 v0 = *(const bf16x8*)(fb + (size_t)s0 * IN_CH);
        bf16x8 v1 = *(const bf16x8*)(fb + (size_t)s1 * IN_CH);
        #pragma unroll
        for (int e = 0; e < 8; ++e) a[e] += b2f((ushort)v0[e]);
        #pragma unroll
        for (int e = 0; e < 8; ++e) a[e] += b2f((ushort)v1[e]);
    }
    for (; j < deg; j += 4) {                  // tail: direct loads, no shfl
        if (j + q < deg) {
            int s = ssrc[beg + j + q];
            bf16x8 v = *(const bf16x8*)(fb + (size_t)s * IN_CH);
            #pragma unroll
            for (int e = 0; e < 8; ++e) a[e] += b2f((ushort)v[e]);
        }
    }

    #pragma unroll
    for (int e = 0; e < 8; ++e) {
        a[e] += __shfl_xor(a[e], 16);
        a[e] += __shfl_xor(a[e], 32);
    }

    if (q == 0) {
        float inv = 1.0f / fmaxf((float)deg, 1.0f);
        union { ushort u[8]; uint4 v; } p;
        #pragma unroll
        for (int e = 0; e < 8; ++e) p.u[e] = f2b(a[e] * inv);
        ((uint4*)(out + (size_t)node * IN_CH))[rr] = p.v;
    }
}

// ---------------- fused layers 1+2 GEMM ----------------
// Phase 1 (layer 1, NT=8): acc = agg@Wl1 + bl1 + x@Wr1, relu, bf16 -> LDS h-tile
//   (per-wave 16x128, padded stride 136 to spread banks).
// Phase 2 (layer 2, NT=4): read h A-fragments from LDS, y2 = bf16(h@Wl2T),
//   s2 = f32(h@Wr2T). h never touches global memory.
__global__ __launch_bounds__(256) void gemm_l12(const ushort* __restrict__ A,
                                                const ushort* __restrict__ B,
                                                const ushort* __restrict__ WlT1,
                                                const ushort* __restrict__ WrT1,
                                                const float* __restrict__ bl1,
                                                const ushort* __restrict__ WlT2,
                                                const ushort* __restrict__ WrT2,
                                                ushort* __restrict__ y2,
                                                float* __restrict__ s2, int nRows) {
    constexpr int HS = 136;                    // padded row stride (bf16 elems)
    __shared__ ushort hs[4][16][HS];

    const int lane = threadIdx.x & 63;
    const int wave = threadIdx.x >> 6;
    const int m0 = blockIdx.x * 64 + wave * 16;
    const int r = lane & 15, g = lane >> 4;
    int row = m0 + r;
    if (row >= nRows) row = nRows - 1;         // clamp loads; stores masked
    const int kc = g * 8;

    // ---- phase 1: layer-1 dual GEMM ----
    f32x4 acc[8];
    #pragma unroll
    for (int i = 0; i < 8; ++i) acc[i] = (f32x4){0.f, 0.f, 0.f, 0.f};

    #pragma unroll
    for (int mat = 0; mat < 2; ++mat) {
        const ushort* __restrict__ Ab = mat ? B : A;
        const ushort* __restrict__ Wb = mat ? WrT1 : WlT1;
        const ushort* arow = Ab + (size_t)row * 128 + kc;
        #pragma unroll
        for (int k0 = 0; k0 < 128; k0 += 32) {
            bf16x8 af = *(const bf16x8*)(arow + k0);
            #pragma unroll
            for (int nt = 0; nt < 8; ++nt) {
                bf16x8 bfv = *(const bf16x8*)(Wb + (size_t)(nt * 16 + r) * 128 + k0 + kc);
                acc[nt] = __builtin_amdgcn_mfma_f32_16x16x32_bf16(af, bfv, acc[nt], 0, 0, 0);
            }
        }
    }

    // bias + relu + deposit h tile into LDS (C-layout: row g*4+q, col nt*16+r)
    #pragma unroll
    for (int nt = 0; nt < 8; ++nt) {
        float bv = bl1[nt * 16 + r];
        #pragma unroll
        for (int q = 0; q < 4; ++q) {
            float v = fmaxf(acc[nt][q] + bv, 0.f);
            hs[wave][g * 4 + q][nt * 16 + r] = f2b(v);
        }
    }
    __syncthreads();

    // ---- phase 2: layer-2 dual GEMM from LDS ----
    f32x4 accl[4], accr[4];
    #pragma unroll
    for (int i = 0; i < 4; ++i) {
        accl[i] = (f32x4){0.f, 0.f, 0.f, 0.f};
        accr[i] = (f32x4){0.f, 0.f, 0.f, 0.f};
    }

    #pragma unroll
    for (int c = 0; c < 4; ++c) {
        bf16x8 af = *(const bf16x8*)(&hs[wave][r][c * 32 + kc]);
        #pragma unroll
        for (int t = 0; t < 4; ++t) {
            bf16x8 wl = *(const bf16x8*)(WlT2 + (size_t)(t * 16 + r) * 128 + c * 32 + kc);
            accl[t] = __builtin_amdgcn_mfma_f32_16x16x32_bf16(af, wl, accl[t], 0, 0, 0);
        }
        #pragma unroll
        for (int t = 0; t < 4; ++t) {
            bf16x8 wr = *(const bf16x8*)(WrT2 + (size_t)(t * 16 + r) * 128 + c * 32 + kc);
            accr[t] = __builtin_amdgcn_mfma_f32_16x16x32_bf16(af, wr, accr[t], 0, 0, 0);
        }
    }

    const int rbase = m0 + g * 4;
    #pragma unroll
    for (int t = 0; t < 4; ++t) {
        #pragma unroll
        for (int q = 0; q < 4; ++q) {
            if (rbase + q < nRows) {
                y2[(size_t)(rbase + q) * 64 + t * 16 + r] = f2b(accl[t][q]);
                s2[(size_t)(rbase + q) * 64 + t * 16 + r] = accr[t][q];
            }
        }
    }
}

// ---------------- layer-2 final: out = log_softmax(mean_agg(y2) + s2 + bias) ----------------
__global__ __launch_bounds__(256) void agg_final(const ushort* __restrict__ y2,
                                                 const float* __restrict__ s2,
                                                 const int* __restrict__ row_ptr,
                                                 const int* __restrict__ ssrc,
                                                 const float* __restrict__ bias,
                                                 float* __restrict__ out, int nNodes) {
    const int node = blockIdx.x * 4 + (threadIdx.x >> 6);
    const int lane = threadIdx.x & 63;
    if (node >= nNodes) return;
    const int q = lane >> 4, rr = lane & 15;
    const int beg = row_ptr[node];
    const int deg = row_ptr[node + 1] - beg;   // wave-uniform

    float a[4] = {0.f, 0.f, 0.f, 0.f};
    const ushort* yb = y2 + rr * 4;
    int idx = 0;
    if (lane < deg) idx = ssrc[beg + lane];
    const int nf8 = min(deg, 64) & ~7;         // wave-uniform, multiple of 8

    #define ACC(vv) { a[0] += b2f((vv).x & 0xffffu); a[1] += b2f((vv).x >> 16); \
                      a[2] += b2f((vv).y & 0xffffu); a[3] += b2f((vv).y >> 16); }
    int j = 0;
    for (; j < nf8; j += 8) {                  // uniform execution: shfl safe
        int s0 = __shfl(idx, j + q);
        int s1 = __shfl(idx, j + 4 + q);
        uint2 v0 = *(const uint2*)(yb + (size_t)s0 * 64);
        uint2 v1 = *(const uint2*)(yb + (size_t)s1 * 64);
        ACC(v0); ACC(v1);
    }
    for (; j < deg; j += 4) {                  // tail: direct loads, no shfl
        if (j + q < deg) {
            int s = ssrc[beg + j + q];
            uint2 v = *(const uint2*)(yb + (size_t)s * 64);
            ACC(v);
        }
    }
    #undef ACC

    #pragma unroll
    for (int e = 0; e < 4; ++e) {
        a[e] += __shfl_xor(a[e], 16);
        a[e] += __shfl_xor(a[e], 32);
    }

    if (q == 0) {
        float inv = 1.0f / fmaxf((float)deg, 1.0f);
        float4 sv = ((const float4*)(s2 + (size_t)node * 64))[rr];
        float4 bv = ((const float4*)bias)[rr];
        float v0 = a[0] * inv + sv.x + bv.x;
        float v1 = a[1] * inv + sv.y + bv.y;
        float v2 = a[2] * inv + sv.z + bv.z;
        float v3 = a[3] * inv + sv.w + bv.w;
        float m = fmaxf(fmaxf(v0, v1), fmaxf(v2, v3));
        #pragma unroll
        for (int off = 8; off >= 1; off >>= 1) m = fmaxf(m, __shfl_xor(m, off));
        float s = expf(v0 - m) + expf(v1 - m) + expf(v2 - m) + expf(v3 - m);
        #pragma unroll
        for (int off = 8; off >= 1; off >>= 1) s += __shfl_xor(s, off);
        float lse = m + logf(s);
        float4 o = {v0 - lse, v1 - lse, v2 - lse, v3 - lse};
        ((float4*)(out + (size_t)node * 64))[rr] = o;
    }
}

extern "C" void kernel_launch(void* const* d_in, const int* in_sizes, int n_in,
                              void* d_out, int out_size, void* d_ws, size_t ws_size,
                              hipStream_t stream) {
    const float* x   = (const float*)d_in[0];
    const int* edges = (const int*)d_in[1];
    const float* Wl1 = (const float*)d_in[2];
    const float* bl1 = (const float*)d_in[3];
    const float* Wr1 = (const float*)d_in[4];
    const float* Wl2 = (const float*)d_in[5];
    const float* bl2 = (const float*)d_in[6];
    const float* Wr2 = (const float*)d_in[7];
    float* out = (float*)d_out;

    const int nN = in_sizes[0] / IN_CH;   // 50000
    const int nE = in_sizes[1] / 2;       // 600000

    // workspace carve
    ushort* xb   = (ushort*)d_ws;                 // nN*128 bf16
    ushort* aggb = xb + (size_t)nN * IN_CH;       // nN*128 bf16 (layer-1 agg)
    ushort* y2   = aggb + (size_t)nN * IN_CH;     // nN*64 bf16
    float*  s2   = (float*)(y2 + (size_t)nN * 64);// nN*64 f32
    ushort* WlT1 = (ushort*)(s2 + (size_t)nN * 64); // 128*128
    ushort* WrT1 = WlT1 + 128 * 128;              // 128*128
    ushort* WlT2 = WrT1 + 128 * 128;              // 64*128
    ushort* WrT2 = WlT2 + 64 * 128;               // 64*128
    int* degI    = (int*)(WrT2 + 64 * 128);       // nN
    int* flags   = degI + nN;                     // 64 (zeroed with degI)
    int* row_ptr = flags + 64;                    // nN+1
    int* bsum    = row_ptr + (nN + 1);            // <=64
    int* ssrc    = bsum + 64;                     // nE
    int* rank    = ssrc + nE;                     // nE

    const int* esrc = edges;
    const int* edst = edges + nE;

    const int n8 = nN * IN_CH / 8;                // 800000
    const int nb = (nN + 1023) / 1024;            // 49 (<=64 required)
    const int nwork = (n8 + 49152 > nE) ? n8 + 49152 : nE;

    hipMemsetAsync(degI, 0, sizeof(int) * (size_t)(nN + 64), stream);  // degI + flags

    prep_hist<<<(nwork + 255) / 256, 256, 0, stream>>>(x, xb, n8,
                                                       Wl1, Wr1, Wl2, Wr2,
                                                       WlT1, WrT1, WlT2, WrT2,
                                                       edst, degI, rank, nE);

    scan_fused<<<nb, 256, 0, stream>>>(degI, bsum, flags, row_ptr, nN, nE);
    scatter_edges<<<(nE + 255) / 256, 256, 0, stream>>>(esrc, edst, row_ptr, rank, ssrc, nE);

    // layer 1 gather
    agg_mean<<<(nN + 3) / 4, 256, 0, stream>>>(xb, row_ptr, ssrc, aggb, nN);

    // fused layer-1 GEMM + layer-2 transform (h stays in LDS)
    gemm_l12<<<(nN + 63) / 64, 256, 0, stream>>>(aggb, xb, WlT1, WrT1, bl1,
                                                 WlT2, WrT2, y2, s2, nN);

    // layer-2 gather + epilogue
    agg_final<<<(nN + 3) / 4, 256, 0, stream>>>(y2, s2, row_ptr, ssrc, bl2, out, nN);
}